// Round 4
// baseline (966.453 us; speedup 1.0000x reference)
//
#include <hip/hip_runtime.h>
#include <hip/hip_bf16.h>

#define DEVI __device__ __forceinline__

namespace {

constexpr int T_   = 8;
constexpr int NTOK = 8192;    // B*S
constexpr int LAT  = 1024;
constexpr int SYM  = 256;
constexpr int NC   = 512;
constexpr float TAU = 0.6f;   // repair margin (approx-score error sigma ~0.07)

typedef short short8 __attribute__((ext_vector_type(8)));
typedef float floatx4 __attribute__((ext_vector_type(4)));

DEVI unsigned short f2bf(float f){
  union { float f; unsigned u; } v; v.f = f;
  return (unsigned short)((v.u + 0x7fffu + ((v.u >> 16) & 1u)) >> 16);
}

// async global->LDS, 16B per lane; LDS dest must be wave-uniform base + lane*16
DEVI void gload_lds16(const void* g, void* l){
  __builtin_amdgcn_global_load_lds((const __attribute__((address_space(1))) void*)g,
                                   (__attribute__((address_space(3))) void*)l, 16, 0, 0);
}

// ---------------- routing: one wave per token -------------------------------
__global__ void route_k(const float* __restrict__ syms, const float* __restrict__ Wq,
                        int* __restrict__ top, int* __restrict__ counts){
  int gt = blockIdx.x * blockDim.x + threadIdx.x;
  int wid = gt >> 6, lane = gt & 63;
  if (wid >= NTOK) return;
  float4 wq = *(const float4*)(Wq + lane * 4);
  float best = -INFINITY; int bt = 0;
  for (int t = 0; t < T_; ++t){
    float4 s = *(const float4*)(syms + ((size_t)t * NTOK + wid) * SYM + lane * 4);
    float p = s.x*wq.x + s.y*wq.y + s.z*wq.z + s.w*wq.w;
    #pragma unroll
    for (int off = 32; off; off >>= 1) p += __shfl_down(p, off, 64);
    p = __shfl(p, 0, 64);
    if (p > best){ best = p; bt = t; }
  }
  if (lane == 0){ top[wid] = bt; atomicAdd(&counts[bt], 1); }
}

// codebook transpose + keep-mask (block 0): cbT[k*NC + c] = cb[c*SYM + k]
__global__ void cbt_k(const float* __restrict__ cb, float* __restrict__ cbT,
                      const int* __restrict__ counts, float* __restrict__ out_mask){
  int i = blockIdx.x * blockDim.x + threadIdx.x;
  if (i < NC * SYM){ int c = i / SYM, k = i % SYM; cbT[k * NC + c] = cb[i]; }
  if (blockIdx.x == 0 && threadIdx.x < T_)
    out_mask[threadIdx.x] = (counts[threadIdx.x] == 0) ? 1.0f : 0.0f;
}

// blocks [0, NC/4): cnorm/svec.  block NC/4: rbias.
__global__ void cnorm_k(const float* __restrict__ cb, const float* __restrict__ bsym,
                        float* __restrict__ cnorm, float* __restrict__ svec,
                        const float* __restrict__ bread, const float* __restrict__ Wsym,
                        float* __restrict__ rb){
  if (blockIdx.x == NC/4){
    // rbias: rb[j] = bsym[j] + sum_k bread[k]*Wsym[k*SYM + j]
    int t = threadIdx.x;
    float a0=0.f,a1=0.f,a2=0.f,a3=0.f;
    for (int k = 0; k < LAT; k += 4){
      a0 += bread[k+0] * Wsym[(size_t)(k+0) * SYM + t];
      a1 += bread[k+1] * Wsym[(size_t)(k+1) * SYM + t];
      a2 += bread[k+2] * Wsym[(size_t)(k+2) * SYM + t];
      a3 += bread[k+3] * Wsym[(size_t)(k+3) * SYM + t];
    }
    rb[t] = bsym[t] + ((a0+a1)+(a2+a3));
    return;
  }
  int gt = blockIdx.x * blockDim.x + threadIdx.x;
  int wid = gt >> 6, lane = gt & 63;
  if (wid >= NC) return;
  float4 v = *(const float4*)(cb + (size_t)wid * SYM + lane * 4);
  float4 b = *(const float4*)(bsym + lane * 4);
  float p = v.x*v.x + v.y*v.y + v.z*v.z + v.w*v.w;
  float q = v.x*(v.x-2.f*b.x) + v.y*(v.y-2.f*b.y) + v.z*(v.z-2.f*b.z) + v.w*(v.w-2.f*b.w);
  #pragma unroll
  for (int off = 32; off; off >>= 1){ p += __shfl_down(p, off, 64); q += __shfl_down(q, off, 64); }
  if (lane == 0){ cnorm[wid] = p; svec[wid] = q; }
}

// fused transpose of the 3 bf16 weight matrices (one dispatch)
__global__ void t32multi_k(const float* __restrict__ Wread, unsigned short* __restrict__ WreadT,
                           const float* __restrict__ Wc1,   unsigned short* __restrict__ Wc1T,
                           const float* __restrict__ Wc2,   unsigned short* __restrict__ Wc2T){
  __shared__ float tile[32][33];
  int b = blockIdx.x;
  const float* in; unsigned short* out; int R, C, t;
  if (b < 2048){ in = Wread; out = WreadT; R = 2*LAT; C = LAT; t = b; }
  else if (b < 2048+1280){ in = Wc1; out = Wc1T; R = LAT+SYM; C = LAT; t = b - 2048; }
  else { in = Wc2; out = Wc2T; R = LAT; C = LAT; t = b - 3328; }
  int bx = t % 32, by = t / 32;
  int r0 = by * 32, c0 = bx * 32;
  int tid = threadIdx.x;
  int tx = tid & 31, ty = tid >> 5;            // ty 0..7
  #pragma unroll
  for (int j = 0; j < 4; ++j)
    tile[ty + j*8][tx] = in[(size_t)(r0 + ty + j*8) * C + c0 + tx];
  __syncthreads();
  #pragma unroll
  for (int j = 0; j < 4; ++j)
    out[(size_t)(c0 + ty + j*8) * R + r0 + tx] = f2bf(tile[tx][ty + j*8]);
}

// ---------------- f32 tiled GEMM (small prep matmuls only) ------------------
// TB=1: write transposed bf16 (Ct[n*M + m]) instead of f32 C.
template<int BM, int BN, int BK, int TM, int TN, int TB>
__global__ __launch_bounds__((BM/TM)*(BN/TN))
void gemm_f32(const float* __restrict__ A, const float* __restrict__ Bm,
              float* __restrict__ Cf, unsigned short* __restrict__ Ct,
              int M, int N, int K)
{
  constexpr int NT  = (BM/TM)*(BN/TN);
  constexpr int BMp = BM + 4, BNp = BN + 4;
  constexpr int KV  = BK / 4;
  constexpr int NLA = BM * KV;
  constexpr int NLB = (BK * BN) / 4;
  __shared__ float As[BK][BMp];
  __shared__ float Bs[BK][BNp];
  const int tid = threadIdx.x;
  const int tx = tid % (BN / TN), ty = tid / (BN / TN);
  const int m0 = blockIdx.x * BM, n0 = blockIdx.y * BN;
  float acc[TM][TN] = {};
  for (int k0 = 0; k0 < K; k0 += BK){
    for (int q = tid; q < NLA; q += NT){
      int m = q / KV, kq = (q % KV) * 4;
      float4 v = *(const float4*)(A + (size_t)(m0+m) * K + k0 + kq);
      As[kq+0][m] = v.x; As[kq+1][m] = v.y; As[kq+2][m] = v.z; As[kq+3][m] = v.w;
    }
    for (int q = tid; q < NLB; q += NT){
      int k = q / (BN/4), n4 = (q % (BN/4)) * 4;
      *(float4*)&Bs[k][n4] = *(const float4*)(Bm + (size_t)(k0+k) * N + n0 + n4);
    }
    __syncthreads();
    #pragma unroll
    for (int k = 0; k < BK; ++k){
      float a[TM], b[TN];
      #pragma unroll
      for (int i = 0; i < TM; ++i) a[i] = As[k][ty*TM + i];
      #pragma unroll
      for (int j = 0; j < TN; ++j) b[j] = Bs[k][tx*TN + j];
      #pragma unroll
      for (int i = 0; i < TM; ++i)
        #pragma unroll
        for (int j = 0; j < TN; ++j) acc[i][j] += a[i] * b[j];
    }
    __syncthreads();
  }
  #pragma unroll
  for (int i = 0; i < TM; ++i)
    #pragma unroll
    for (int j = 0; j < TN; ++j){
      if constexpr (TB){
        Ct[(size_t)(n0 + tx*TN + j) * M + m0 + ty*TM + i] = f2bf(acc[i][j]);
      } else {
        Cf[(size_t)(m0 + ty*TM + i) * N + n0 + tx*TN + j] = acc[i][j];
      }
    }
}

// ---------------- MFMA bf16 GEMM: C = A @ BT^T ------------------------------
// A [M x K] bf16 RM; A_CAT: two bf16 sources split at asplit.
// A_F32CAT: A-side gathered from f32 ts / bus[top[m]] with on-the-fly bf16
//           convert (fused pack_az); B-side stays global_load_lds.
// 128x128 tile, BK=32, 4 waves (2x2), each wave 64x64 = 4x4 mfma_16x16x32.
constexpr int A_PLAIN = 0, A_CAT = 1, A_F32CAT = 2;
constexpr int EP_ZH = 0, EP_VQ = 1, EP_RELU = 2, EP_OUT = 3;

template<int ASRC, int EPI>
__global__ __launch_bounds__(256)
void mgemm(const unsigned short* __restrict__ A, const unsigned short* __restrict__ A2,
           const unsigned short* __restrict__ BT, const float* __restrict__ bias,
           const float* __restrict__ resid,
           unsigned short* __restrict__ Cb, float* __restrict__ Cf,
           int N, int K, int asplit,
           const float* __restrict__ Af, const float* __restrict__ A2f,
           const int* __restrict__ topp)
{
  __shared__ unsigned short As[128*32];
  __shared__ unsigned short Bs[128*32];
  __shared__ int topl[128];
  const int tid  = threadIdx.x;
  const int wave = tid >> 6, lane = tid & 63;
  const int wy = wave >> 1, wx = wave & 1;
  const int lq = lane >> 4, lr = lane & 15;
  const int m0 = blockIdx.y * 128, n0 = blockIdx.x * 128;

  if constexpr (ASRC == A_F32CAT){
    if (tid < 128) topl[tid] = topp[m0 + tid];
    __syncthreads();
  }

  floatx4 acc[4][4] = {};

  for (int k0 = 0; k0 < K; k0 += 32){
    #pragma unroll
    for (int c = 0; c < 2; ++c){
      int chunk = tid + c*256;                 // 0..511
      int mrel = chunk >> 2, kc = (chunk & 3) * 8;
      int gk = k0 + kc;
      if constexpr (ASRC == A_F32CAT){
        const float* sf;
        if (gk < asplit) sf = Af + (size_t)(m0+mrel) * asplit + gk;
        else sf = A2f + ((size_t)topl[mrel] * NTOK + (m0+mrel)) * (size_t)(K-asplit) + (gk-asplit);
        float4 v0 = *(const float4*)sf;
        float4 v1 = *(const float4*)(sf + 4);
        short8 o;
        o[0]=(short)f2bf(v0.x); o[1]=(short)f2bf(v0.y); o[2]=(short)f2bf(v0.z); o[3]=(short)f2bf(v0.w);
        o[4]=(short)f2bf(v1.x); o[5]=(short)f2bf(v1.y); o[6]=(short)f2bf(v1.z); o[7]=(short)f2bf(v1.w);
        *(short8*)&As[chunk*8] = o;
      } else {
        const unsigned short* srcA;
        if constexpr (ASRC == A_CAT){
          if (gk < asplit) srcA = A  + (size_t)(m0+mrel) * asplit + gk;
          else             srcA = A2 + (size_t)(m0+mrel) * (K-asplit) + (gk-asplit);
        } else {
          srcA = A + (size_t)(m0+mrel) * K + gk;
        }
        gload_lds16(srcA, &As[(c*256 + wave*64) * 8]);
      }
      gload_lds16(BT + (size_t)(n0+mrel) * K + gk, &Bs[(c*256 + wave*64) * 8]);
    }
    __syncthreads();
    short8 af[4], bf[4];
    #pragma unroll
    for (int i = 0; i < 4; ++i){
      af[i] = *(const short8*)&As[(wy*64 + i*16 + lr)*32 + lq*8];
      bf[i] = *(const short8*)&Bs[(wx*64 + i*16 + lr)*32 + lq*8];
    }
    #pragma unroll
    for (int i = 0; i < 4; ++i)
      #pragma unroll
      for (int j = 0; j < 4; ++j)
        acc[i][j] = __builtin_amdgcn_mfma_f32_16x16x32_bf16(af[i], bf[j], acc[i][j], 0, 0, 0);
    __syncthreads();
  }

  #pragma unroll
  for (int i = 0; i < 4; ++i){
    #pragma unroll
    for (int j = 0; j < 4; ++j){
      int gn = n0 + wx*64 + j*16 + lr;
      #pragma unroll
      for (int r = 0; r < 4; ++r){
        int gm = m0 + wy*64 + i*16 + lq*4 + r;
        float v = acc[i][j][r];
        if constexpr (EPI == EP_ZH){
          Cb[(size_t)gm * N + gn] = f2bf(v + bias[gn]);
        } else if constexpr (EPI == EP_VQ){
          Cf[(size_t)gm * N + gn] = bias[gn] - 2.f * v;     // bias = svec
        } else if constexpr (EPI == EP_RELU){
          float u = v + bias[gn];
          Cb[(size_t)gm * N + gn] = f2bf(u > 0.f ? u : 0.f);
        } else {
          Cf[(size_t)gm * N + gn] = v + bias[gn] + resid[(size_t)gm * N + gn];
        }
      }
    }
  }
}

// ---------------- VQ: top-2 margin argmin + gather + repair flagging --------
__global__ void vq_k(const float* __restrict__ scores, const float* __restrict__ cb,
                     float* __restrict__ out_q, float* __restrict__ out_idx,
                     unsigned short* __restrict__ q_h,
                     int* __restrict__ rcount, int* __restrict__ rlist){
  int gt = blockIdx.x * blockDim.x + threadIdx.x;
  int wid = gt >> 6, lane = gt & 63;
  if (wid >= NTOK) return;
  const float* row = scores + (size_t)wid * NC;
  float v1 = INFINITY, v2 = INFINITY; int i1 = 0x7fffffff;
  #pragma unroll
  for (int i = 0; i < NC/64; ++i){
    int c = i*64 + lane;
    float v = row[c];
    if (v < v1){ v2 = v1; v1 = v; i1 = c; } else v2 = fminf(v2, v);
  }
  #pragma unroll
  for (int off = 32; off; off >>= 1){
    float ov1 = __shfl_down(v1, off, 64);
    int   oi1 = __shfl_down(i1, off, 64);
    float ov2 = __shfl_down(v2, off, 64);
    float rest;
    if (ov1 < v1 || (ov1 == v1 && oi1 < i1)){ rest = v1; v1 = ov1; i1 = oi1; }
    else rest = ov1;
    v2 = fminf(fminf(v2, ov2), rest);
  }
  i1 = __shfl(i1, 0, 64);
  if (lane == 0){
    out_idx[wid] = (float)i1;
    if (__shfl(v2, 0, 64) - __shfl(v1, 0, 64) < TAU){
      int p = atomicAdd(rcount, 1); rlist[p] = wid;
    }
  }
  float4 cv = *(const float4*)(cb + (size_t)i1 * SYM + lane * 4);
  *(float4*)(out_q + (size_t)wid * SYM + lane * 4) = cv;
  ushort4 qh; qh.x = f2bf(cv.x); qh.y = f2bf(cv.y); qh.z = f2bf(cv.z); qh.w = f2bf(cv.w);
  *(ushort4*)(q_h + (size_t)wid * SYM + lane * 4) = qh;
}

// ---------------- exact f32 repair for near-tie tokens ----------------------
constexpr int RT = 4;

__global__ __launch_bounds__(256)
void repair_k(const int* __restrict__ rcount, const int* __restrict__ rlist,
              const int* __restrict__ top,
              const float* __restrict__ ts, const float* __restrict__ bus,
              const float* __restrict__ Wcomb, const float* __restrict__ rb,
              const float* __restrict__ cb, const float* __restrict__ cnorm,
              float* __restrict__ out_q, float* __restrict__ out_idx,
              unsigned short* __restrict__ q_h){
  __shared__ float a[RT][2*LAT];       // 32 KB
  __shared__ float raw[RT][SYM];       // 4 KB
  __shared__ float pv[RT][4];
  __shared__ int   pi[RT][4];
  __shared__ int   fidx[RT];
  int tid = threadIdx.x;
  int lane = tid & 63, wave = tid >> 6;
  int cnt = *rcount;
  int nchunk = (cnt + RT - 1) / RT;
  for (int ch = blockIdx.x; ch < nchunk; ch += gridDim.x){
    int base = ch * RT;
    int nt = min(RT, cnt - base);
    for (int q = tid; q < nt * 512; q += 256){
      int t = q >> 9, c = (q & 511) * 4;
      int m = rlist[base + t];
      int tp = top[m];
      float4 v = (c < LAT) ? *(const float4*)(ts + (size_t)m * LAT + c)
                           : *(const float4*)(bus + ((size_t)tp * NTOK + m) * LAT + (c - LAT));
      *(float4*)&a[t][c] = v;
    }
    __syncthreads();
    float acc0[RT], acc1[RT], acc2[RT], acc3[RT];
    #pragma unroll
    for (int t = 0; t < RT; ++t){ acc0[t]=0.f; acc1[t]=0.f; acc2[t]=0.f; acc3[t]=0.f; }
    for (int k = 0; k < 2*LAT; k += 4){
      float w0 = Wcomb[(size_t)(k+0) * SYM + tid];
      float w1 = Wcomb[(size_t)(k+1) * SYM + tid];
      float w2 = Wcomb[(size_t)(k+2) * SYM + tid];
      float w3 = Wcomb[(size_t)(k+3) * SYM + tid];
      #pragma unroll
      for (int t = 0; t < RT; ++t){
        float4 av = *(const float4*)&a[t][k];
        acc0[t] += av.x * w0; acc1[t] += av.y * w1;
        acc2[t] += av.z * w2; acc3[t] += av.w * w3;
      }
    }
    #pragma unroll
    for (int t = 0; t < RT; ++t)
      raw[t][tid] = rb[tid] + ((acc0[t] + acc1[t]) + (acc2[t] + acc3[t]));
    __syncthreads();
    float bv[RT]; int bi[RT];
    #pragma unroll
    for (int t = 0; t < RT; ++t){ bv[t] = INFINITY; bi[t] = 0x7fffffff; }
    #pragma unroll
    for (int cc = 0; cc < 2; ++cc){
      int c = tid + cc * 256;
      const float* cr = cb + (size_t)c * SYM;
      float d[RT] = {};
      for (int j = 0; j < SYM; j += 4){
        float4 cv = *(const float4*)(cr + j);
        #pragma unroll
        for (int t = 0; t < RT; ++t){
          float4 rv4 = *(const float4*)&raw[t][j];
          d[t] += rv4.x*cv.x + rv4.y*cv.y + rv4.z*cv.z + rv4.w*cv.w;
        }
      }
      #pragma unroll
      for (int t = 0; t < RT; ++t){
        float s = cnorm[c] - 2.f * d[t];
        if (s < bv[t] || (s == bv[t] && c < bi[t])){ bv[t] = s; bi[t] = c; }
      }
    }
    #pragma unroll
    for (int t = 0; t < RT; ++t){
      float v = bv[t]; int i = bi[t];
      #pragma unroll
      for (int off = 32; off; off >>= 1){
        float ov = __shfl_down(v, off, 64);
        int   oi = __shfl_down(i, off, 64);
        if (ov < v || (ov == v && oi < i)){ v = ov; i = oi; }
      }
      if (lane == 0){ pv[t][wave] = v; pi[t][wave] = i; }
    }
    __syncthreads();
    if (tid < nt){
      float v = pv[tid][0]; int i = pi[tid][0];
      #pragma unroll
      for (int w = 1; w < 4; ++w){
        if (pv[tid][w] < v || (pv[tid][w] == v && pi[tid][w] < i)){ v = pv[tid][w]; i = pi[tid][w]; }
      }
      fidx[tid] = i;
      out_idx[rlist[base + tid]] = (float)i;
    }
    __syncthreads();
    for (int t = 0; t < nt; ++t){
      int m = rlist[base + t];
      int idx = fidx[t];
      float cvv = cb[(size_t)idx * SYM + tid];
      out_q[(size_t)m * SYM + tid] = cvv;
      q_h[(size_t)m * SYM + tid] = f2bf(cvv);
    }
    __syncthreads();   // protect a/raw/fidx reuse across chunks
  }
}

} // namespace

extern "C" void kernel_launch(void* const* d_in, const int* in_sizes, int n_in,
                              void* d_out, int out_size, void* d_ws, size_t ws_size,
                              hipStream_t stream){
  const float* token_state = (const float*)d_in[0];
  const float* bus_symbols = (const float*)d_in[1];
  const float* bus_outputs = (const float*)d_in[3];
  const float* Wq    = (const float*)d_in[5];
  const float* Wread = (const float*)d_in[7];
  const float* bread = (const float*)d_in[8];
  const float* Wsym  = (const float*)d_in[9];
  const float* bsym  = (const float*)d_in[10];
  const float* Wc1   = (const float*)d_in[11];
  const float* bc1   = (const float*)d_in[12];
  const float* Wc2   = (const float*)d_in[13];
  const float* bc2   = (const float*)d_in[14];
  const float* codebook = (const float*)d_in[15];

  float* out_node = (float*)d_out;                       // [NTOK*LAT]
  float* out_quant= out_node + (size_t)NTOK * LAT;       // [NTOK*SYM]
  float* out_idx  = out_quant + (size_t)NTOK * SYM;      // [NTOK]
  float* out_mask = out_idx + NTOK;                      // [T]

  // ---- workspace layout (256B aligned) ----
  char* W = (char*)d_ws; size_t off = 0;
  auto alloc = [&](size_t bytes)->char*{ char* p = W + off; off = (off + bytes + 255) & ~(size_t)255; return p; };
  int*   top     = (int*)alloc(NTOK*4);
  char*  zeroed  = alloc(256);              // counts (32B) + rcount (@128), one memset
  int*   counts  = (int*)zeroed;
  int*   rcount  = (int*)(zeroed + 128);
  int*   rlist   = (int*)alloc(NTOK*4);
  float* cbT     = (float*)alloc((size_t)SYM*NC*4);
  float* cnorm   = (float*)alloc(NC*4);
  float* svec    = (float*)alloc(NC*4);
  float* rb      = (float*)alloc(SYM*4);
  float* Wcomb   = (float*)alloc((size_t)2*LAT*SYM*4);
  unsigned short* WreadT = (unsigned short*)alloc((size_t)LAT*2*LAT*2);
  unsigned short* Wc1T   = (unsigned short*)alloc((size_t)LAT*(LAT+SYM)*2);
  unsigned short* Wc2T   = (unsigned short*)alloc((size_t)LAT*LAT*2);
  unsigned short* WfuseT = (unsigned short*)alloc((size_t)NC*LAT*2);
  unsigned short* z_h    = (unsigned short*)alloc((size_t)NTOK*LAT*2);
  unsigned short* q_h    = (unsigned short*)alloc((size_t)NTOK*SYM*2);
  unsigned short* h_h    = (unsigned short*)alloc((size_t)NTOK*LAT*2);
  float* scores          = (float*)alloc((size_t)NTOK*NC*4);

  hipMemsetAsync(zeroed, 0, 256, stream);

  route_k<<<NTOK/4, 256, 0, stream>>>(bus_symbols, Wq, top, counts);
  cbt_k<<<(NC*SYM)/256, 256, 0, stream>>>(codebook, cbT, counts, out_mask);
  cnorm_k<<<NC/4 + 1, 256, 0, stream>>>(codebook, bsym, cnorm, svec, bread, Wsym, rb);

  // WfuseT = bf16((Wsym @ cbT)^T)  [NC x LAT], fused transpose epilogue
  gemm_f32<64,64,8,4,4,1><<<dim3(LAT/64, NC/64), 256, 0, stream>>>(
      Wsym, cbT, nullptr, WfuseT, LAT, NC, SYM);
  // Wcomb = Wread @ Wsym  [2LAT x SYM] f32 (repair path); 32-row tiles -> 256 blocks
  gemm_f32<32,64,8,2,4,0><<<dim3(2*LAT/32, SYM/64), 256, 0, stream>>>(
      Wread, Wsym, Wcomb, nullptr, 2*LAT, SYM, LAT);
  // all three weight transposes in one dispatch
  t32multi_k<<<2048+1280+1024, 256, 0, stream>>>(Wread, WreadT, Wc1, Wc1T, Wc2, Wc2T);

  // z_h = bf16([ts | bus[top]] @ WreadT^T + bread)   (pack_az fused into A-staging)
  mgemm<A_F32CAT, EP_ZH><<<dim3(LAT/128, NTOK/128), 256, 0, stream>>>(
      nullptr, nullptr, WreadT, bread, nullptr, z_h, nullptr, LAT, 2*LAT, LAT,
      token_state, bus_outputs, top);
  // scores = svec - 2 * z_h @ WfuseT^T   [NTOK x NC] f32
  mgemm<A_PLAIN, EP_VQ><<<dim3(NC/128, NTOK/128), 256, 0, stream>>>(
      z_h, nullptr, WfuseT, svec, nullptr, nullptr, scores, NC, LAT, 0,
      nullptr, nullptr, nullptr);

  vq_k<<<NTOK/4, 256, 0, stream>>>(scores, codebook, out_quant, out_idx, q_h, rcount, rlist);
  repair_k<<<512, 256, 0, stream>>>(rcount, rlist, top, token_state, bus_outputs,
                                    Wcomb, rb, codebook, cnorm, out_quant, out_idx, q_h);

  // h_h = bf16(relu([z_h | q_h] @ Wc1T^T + bc1))
  mgemm<A_CAT, EP_RELU><<<dim3(LAT/128, NTOK/128), 256, 0, stream>>>(
      z_h, q_h, Wc1T, bc1, nullptr, h_h, nullptr, LAT, LAT+SYM, LAT,
      nullptr, nullptr, nullptr);
  // out_node = h_h @ Wc2T^T + bc2 + token_state   (f32)
  mgemm<A_PLAIN, EP_OUT><<<dim3(LAT/128, NTOK/128), 256, 0, stream>>>(
      h_h, nullptr, Wc2T, bc2, token_state, nullptr, out_node, LAT, LAT, 0,
      nullptr, nullptr, nullptr);
}

// Round 5
// 905.855 us; speedup vs baseline: 1.0669x; 1.0669x over previous
//
#include <hip/hip_runtime.h>
#include <hip/hip_bf16.h>

#define DEVI __device__ __forceinline__

namespace {

constexpr int T_   = 8;
constexpr int NTOK = 8192;    // B*S
constexpr int LAT  = 1024;
constexpr int SYM  = 256;
constexpr int NC   = 512;
constexpr float TAU = 0.6f;   // repair margin (approx-score error sigma ~0.07)

typedef short short8 __attribute__((ext_vector_type(8)));
typedef float floatx4 __attribute__((ext_vector_type(4)));

DEVI unsigned short f2bf(float f){
  union { float f; unsigned u; } v; v.f = f;
  return (unsigned short)((v.u + 0x7fffu + ((v.u >> 16) & 1u)) >> 16);
}

// async global->LDS, 16B per lane; LDS dest must be wave-uniform base + lane*16
DEVI void gload_lds16(const void* g, void* l){
  __builtin_amdgcn_global_load_lds((const __attribute__((address_space(1))) void*)g,
                                   (__attribute__((address_space(3))) void*)l, 16, 0, 0);
}

// ---------------- routing: one wave per token -------------------------------
__global__ void route_k(const float* __restrict__ syms, const float* __restrict__ Wq,
                        int* __restrict__ top, int* __restrict__ counts){
  int gt = blockIdx.x * blockDim.x + threadIdx.x;
  int wid = gt >> 6, lane = gt & 63;
  if (wid >= NTOK) return;
  float4 wq = *(const float4*)(Wq + lane * 4);
  float best = -INFINITY; int bt = 0;
  for (int t = 0; t < T_; ++t){
    float4 s = *(const float4*)(syms + ((size_t)t * NTOK + wid) * SYM + lane * 4);
    float p = s.x*wq.x + s.y*wq.y + s.z*wq.z + s.w*wq.w;
    #pragma unroll
    for (int off = 32; off; off >>= 1) p += __shfl_down(p, off, 64);
    p = __shfl(p, 0, 64);
    if (p > best){ best = p; bt = t; }
  }
  if (lane == 0){ top[wid] = bt; atomicAdd(&counts[bt], 1); }
}

// codebook transpose + keep-mask (block 0): cbT[k*NC + c] = cb[c*SYM + k]
__global__ void cbt_k(const float* __restrict__ cb, float* __restrict__ cbT,
                      const int* __restrict__ counts, float* __restrict__ out_mask){
  int i = blockIdx.x * blockDim.x + threadIdx.x;
  if (i < NC * SYM){ int c = i / SYM, k = i % SYM; cbT[k * NC + c] = cb[i]; }
  if (blockIdx.x == 0 && threadIdx.x < T_)
    out_mask[threadIdx.x] = (counts[threadIdx.x] == 0) ? 1.0f : 0.0f;
}

// blocks [0, NC/4): cnorm/svec.  block NC/4: rbias.
__global__ void cnorm_k(const float* __restrict__ cb, const float* __restrict__ bsym,
                        float* __restrict__ cnorm, float* __restrict__ svec,
                        const float* __restrict__ bread, const float* __restrict__ Wsym,
                        float* __restrict__ rb){
  if (blockIdx.x == NC/4){
    int t = threadIdx.x;
    float a0=0.f,a1=0.f,a2=0.f,a3=0.f;
    for (int k = 0; k < LAT; k += 4){
      a0 += bread[k+0] * Wsym[(size_t)(k+0) * SYM + t];
      a1 += bread[k+1] * Wsym[(size_t)(k+1) * SYM + t];
      a2 += bread[k+2] * Wsym[(size_t)(k+2) * SYM + t];
      a3 += bread[k+3] * Wsym[(size_t)(k+3) * SYM + t];
    }
    rb[t] = bsym[t] + ((a0+a1)+(a2+a3));
    return;
  }
  int gt = blockIdx.x * blockDim.x + threadIdx.x;
  int wid = gt >> 6, lane = gt & 63;
  if (wid >= NC) return;
  float4 v = *(const float4*)(cb + (size_t)wid * SYM + lane * 4);
  float4 b = *(const float4*)(bsym + lane * 4);
  float p = v.x*v.x + v.y*v.y + v.z*v.z + v.w*v.w;
  float q = v.x*(v.x-2.f*b.x) + v.y*(v.y-2.f*b.y) + v.z*(v.z-2.f*b.z) + v.w*(v.w-2.f*b.w);
  #pragma unroll
  for (int off = 32; off; off >>= 1){ p += __shfl_down(p, off, 64); q += __shfl_down(q, off, 64); }
  if (lane == 0){ cnorm[wid] = p; svec[wid] = q; }
}

// fused transpose of the 3 bf16 weight matrices (one dispatch)
__global__ void t32multi_k(const float* __restrict__ Wread, unsigned short* __restrict__ WreadT,
                           const float* __restrict__ Wc1,   unsigned short* __restrict__ Wc1T,
                           const float* __restrict__ Wc2,   unsigned short* __restrict__ Wc2T){
  __shared__ float tile[32][33];
  int b = blockIdx.x;
  const float* in; unsigned short* out; int R, C, t;
  if (b < 2048){ in = Wread; out = WreadT; R = 2*LAT; C = LAT; t = b; }
  else if (b < 2048+1280){ in = Wc1; out = Wc1T; R = LAT+SYM; C = LAT; t = b - 2048; }
  else { in = Wc2; out = Wc2T; R = LAT; C = LAT; t = b - 3328; }
  int bx = t % 32, by = t / 32;
  int r0 = by * 32, c0 = bx * 32;
  int tid = threadIdx.x;
  int tx = tid & 31, ty = tid >> 5;            // ty 0..7
  #pragma unroll
  for (int j = 0; j < 4; ++j)
    tile[ty + j*8][tx] = in[(size_t)(r0 + ty + j*8) * C + c0 + tx];
  __syncthreads();
  #pragma unroll
  for (int j = 0; j < 4; ++j)
    out[(size_t)(c0 + ty + j*8) * R + r0 + tx] = f2bf(tile[tx][ty + j*8]);
}

// pack A_z bf16 [NTOK x 2*LAT] = [bf16(token_state) | bf16(bus_outputs[top])]
__global__ void pack_az(const float* __restrict__ ts, const float* __restrict__ bus,
                        const int* __restrict__ top, unsigned short* __restrict__ Az){
  int id = blockIdx.x * blockDim.x + threadIdx.x;
  int m = id >> 9, c = (id & 511) * 4;
  const float* src = (c < LAT) ? (ts + (size_t)m * LAT + c)
                               : (bus + ((size_t)top[m] * NTOK + m) * LAT + (c - LAT));
  float4 v = *(const float4*)src;
  ushort4 o; o.x = f2bf(v.x); o.y = f2bf(v.y); o.z = f2bf(v.z); o.w = f2bf(v.w);
  *(ushort4*)(Az + (size_t)m * (2*LAT) + c) = o;
}

// ---------------- f32 tiled GEMM (small prep matmuls only) ------------------
// TB=1: write transposed bf16 (Ct[n*M + m]) instead of f32 C.
template<int BM, int BN, int BK, int TM, int TN, int TB>
__global__ __launch_bounds__((BM/TM)*(BN/TN))
void gemm_f32(const float* __restrict__ A, const float* __restrict__ Bm,
              float* __restrict__ Cf, unsigned short* __restrict__ Ct,
              int M, int N, int K)
{
  constexpr int NT  = (BM/TM)*(BN/TN);
  constexpr int BMp = BM + 4, BNp = BN + 4;
  constexpr int KV  = BK / 4;
  constexpr int NLA = BM * KV;
  constexpr int NLB = (BK * BN) / 4;
  __shared__ float As[BK][BMp];
  __shared__ float Bs[BK][BNp];
  const int tid = threadIdx.x;
  const int tx = tid % (BN / TN), ty = tid / (BN / TN);
  const int m0 = blockIdx.x * BM, n0 = blockIdx.y * BN;
  float acc[TM][TN] = {};
  for (int k0 = 0; k0 < K; k0 += BK){
    for (int q = tid; q < NLA; q += NT){
      int m = q / KV, kq = (q % KV) * 4;
      float4 v = *(const float4*)(A + (size_t)(m0+m) * K + k0 + kq);
      As[kq+0][m] = v.x; As[kq+1][m] = v.y; As[kq+2][m] = v.z; As[kq+3][m] = v.w;
    }
    for (int q = tid; q < NLB; q += NT){
      int k = q / (BN/4), n4 = (q % (BN/4)) * 4;
      *(float4*)&Bs[k][n4] = *(const float4*)(Bm + (size_t)(k0+k) * N + n0 + n4);
    }
    __syncthreads();
    #pragma unroll
    for (int k = 0; k < BK; ++k){
      float a[TM], b[TN];
      #pragma unroll
      for (int i = 0; i < TM; ++i) a[i] = As[k][ty*TM + i];
      #pragma unroll
      for (int j = 0; j < TN; ++j) b[j] = Bs[k][tx*TN + j];
      #pragma unroll
      for (int i = 0; i < TM; ++i)
        #pragma unroll
        for (int j = 0; j < TN; ++j) acc[i][j] += a[i] * b[j];
    }
    __syncthreads();
  }
  #pragma unroll
  for (int i = 0; i < TM; ++i)
    #pragma unroll
    for (int j = 0; j < TN; ++j){
      if constexpr (TB){
        Ct[(size_t)(n0 + tx*TN + j) * M + m0 + ty*TM + i] = f2bf(acc[i][j]);
      } else {
        Cf[(size_t)(m0 + ty*TM + i) * N + n0 + tx*TN + j] = acc[i][j];
      }
    }
}

// ---------------- MFMA bf16 GEMM: C = A @ BT^T ------------------------------
// A [M x K] bf16 RM (CAT: A stride asplit, A2 stride K-asplit), BT [N x K] bf16 RM.
// 128x128 tile, BK=32, 4 waves (2x2), each wave 64x64 = 4x4 mfma_16x16x32.
// Staging via global_load_lds width=16; LDS linear both sides.
// XCD-aware bijective block swizzle: consecutive linear block IDs share the
// A-panel (same by); remap so each XCD owns a contiguous chunk of by-panels
// (A-panels become L2-resident per XCD; B fits L2). Requires nwg % 8 == 0,
// true for all four call sites (512/256/512/512 blocks).
constexpr int A_PLAIN = 0, A_CAT = 1;
constexpr int EP_ZH = 0, EP_VQ = 1, EP_RELU = 2, EP_OUT = 3;

template<int ASRC, int EPI>
__global__ __launch_bounds__(256)
void mgemm(const unsigned short* __restrict__ A, const unsigned short* __restrict__ A2,
           const unsigned short* __restrict__ BT, const float* __restrict__ bias,
           const float* __restrict__ resid,
           unsigned short* __restrict__ Cb, float* __restrict__ Cf,
           int N, int K, int asplit)
{
  __shared__ unsigned short As[128*32];
  __shared__ unsigned short Bs[128*32];
  const int tid  = threadIdx.x;
  const int wave = tid >> 6, lane = tid & 63;
  const int wy = wave >> 1, wx = wave & 1;
  const int lq = lane >> 4, lr = lane & 15;

  // XCD swizzle (bijective since nwg % 8 == 0)
  const int nwg  = gridDim.x * gridDim.y;
  const int orig = blockIdx.y * gridDim.x + blockIdx.x;
  const int dec  = (orig & 7) * (nwg >> 3) + (orig >> 3);
  const int bx   = dec % gridDim.x, by = dec / gridDim.x;
  const int m0 = by * 128, n0 = bx * 128;

  floatx4 acc[4][4] = {};

  for (int k0 = 0; k0 < K; k0 += 32){
    #pragma unroll
    for (int c = 0; c < 2; ++c){
      int chunk = tid + c*256;                 // 0..511
      int mrel = chunk >> 2, kc = (chunk & 3) * 8;
      int gk = k0 + kc;
      const unsigned short* srcA;
      if constexpr (ASRC == A_CAT){
        if (gk < asplit) srcA = A  + (size_t)(m0+mrel) * asplit + gk;
        else             srcA = A2 + (size_t)(m0+mrel) * (K-asplit) + (gk-asplit);
      } else {
        srcA = A + (size_t)(m0+mrel) * K + gk;
      }
      gload_lds16(srcA, &As[(c*256 + wave*64) * 8]);
      gload_lds16(BT + (size_t)(n0+mrel) * K + gk, &Bs[(c*256 + wave*64) * 8]);
    }
    __syncthreads();
    short8 af[4], bf[4];
    #pragma unroll
    for (int i = 0; i < 4; ++i){
      af[i] = *(const short8*)&As[(wy*64 + i*16 + lr)*32 + lq*8];
      bf[i] = *(const short8*)&Bs[(wx*64 + i*16 + lr)*32 + lq*8];
    }
    #pragma unroll
    for (int i = 0; i < 4; ++i)
      #pragma unroll
      for (int j = 0; j < 4; ++j)
        acc[i][j] = __builtin_amdgcn_mfma_f32_16x16x32_bf16(af[i], bf[j], acc[i][j], 0, 0, 0);
    __syncthreads();
  }

  #pragma unroll
  for (int i = 0; i < 4; ++i){
    #pragma unroll
    for (int j = 0; j < 4; ++j){
      int gn = n0 + wx*64 + j*16 + lr;
      #pragma unroll
      for (int r = 0; r < 4; ++r){
        int gm = m0 + wy*64 + i*16 + lq*4 + r;
        float v = acc[i][j][r];
        if constexpr (EPI == EP_ZH){
          Cb[(size_t)gm * N + gn] = f2bf(v + bias[gn]);
        } else if constexpr (EPI == EP_VQ){
          Cf[(size_t)gm * N + gn] = bias[gn] - 2.f * v;     // bias = svec
        } else if constexpr (EPI == EP_RELU){
          float u = v + bias[gn];
          Cb[(size_t)gm * N + gn] = f2bf(u > 0.f ? u : 0.f);
        } else {
          Cf[(size_t)gm * N + gn] = v + bias[gn] + resid[(size_t)gm * N + gn];
        }
      }
    }
  }
}

// ---------------- VQ: top-2 margin argmin + gather + repair flagging --------
__global__ void vq_k(const float* __restrict__ scores, const float* __restrict__ cb,
                     float* __restrict__ out_q, float* __restrict__ out_idx,
                     unsigned short* __restrict__ q_h,
                     int* __restrict__ rcount, int* __restrict__ rlist){
  int gt = blockIdx.x * blockDim.x + threadIdx.x;
  int wid = gt >> 6, lane = gt & 63;
  if (wid >= NTOK) return;
  const float* row = scores + (size_t)wid * NC;
  float v1 = INFINITY, v2 = INFINITY; int i1 = 0x7fffffff;
  #pragma unroll
  for (int i = 0; i < NC/64; ++i){
    int c = i*64 + lane;
    float v = row[c];
    if (v < v1){ v2 = v1; v1 = v; i1 = c; } else v2 = fminf(v2, v);
  }
  #pragma unroll
  for (int off = 32; off; off >>= 1){
    float ov1 = __shfl_down(v1, off, 64);
    int   oi1 = __shfl_down(i1, off, 64);
    float ov2 = __shfl_down(v2, off, 64);
    float rest;
    if (ov1 < v1 || (ov1 == v1 && oi1 < i1)){ rest = v1; v1 = ov1; i1 = oi1; }
    else rest = ov1;
    v2 = fminf(fminf(v2, ov2), rest);
  }
  i1 = __shfl(i1, 0, 64);
  if (lane == 0){
    out_idx[wid] = (float)i1;
    if (__shfl(v2, 0, 64) - __shfl(v1, 0, 64) < TAU){
      int p = atomicAdd(rcount, 1); rlist[p] = wid;
    }
  }
  float4 cv = *(const float4*)(cb + (size_t)i1 * SYM + lane * 4);
  *(float4*)(out_q + (size_t)wid * SYM + lane * 4) = cv;
  ushort4 qh; qh.x = f2bf(cv.x); qh.y = f2bf(cv.y); qh.z = f2bf(cv.z); qh.w = f2bf(cv.w);
  *(ushort4*)(q_h + (size_t)wid * SYM + lane * 4) = qh;
}

// ---------------- exact f32 repair for near-tie tokens ----------------------
constexpr int RT = 4;

__global__ __launch_bounds__(256)
void repair_k(const int* __restrict__ rcount, const int* __restrict__ rlist,
              const int* __restrict__ top,
              const float* __restrict__ ts, const float* __restrict__ bus,
              const float* __restrict__ Wcomb, const float* __restrict__ rb,
              const float* __restrict__ cb, const float* __restrict__ cnorm,
              float* __restrict__ out_q, float* __restrict__ out_idx,
              unsigned short* __restrict__ q_h){
  __shared__ float a[RT][2*LAT];       // 32 KB
  __shared__ float raw[RT][SYM];       // 4 KB
  __shared__ float pv[RT][4];
  __shared__ int   pi[RT][4];
  __shared__ int   fidx[RT];
  int tid = threadIdx.x;
  int lane = tid & 63, wave = tid >> 6;
  int cnt = *rcount;
  int nchunk = (cnt + RT - 1) / RT;
  for (int ch = blockIdx.x; ch < nchunk; ch += gridDim.x){
    int base = ch * RT;
    int nt = min(RT, cnt - base);
    for (int q = tid; q < nt * 512; q += 256){
      int t = q >> 9, c = (q & 511) * 4;
      int m = rlist[base + t];
      int tp = top[m];
      float4 v = (c < LAT) ? *(const float4*)(ts + (size_t)m * LAT + c)
                           : *(const float4*)(bus + ((size_t)tp * NTOK + m) * LAT + (c - LAT));
      *(float4*)&a[t][c] = v;
    }
    __syncthreads();
    float acc0[RT], acc1[RT], acc2[RT], acc3[RT];
    #pragma unroll
    for (int t = 0; t < RT; ++t){ acc0[t]=0.f; acc1[t]=0.f; acc2[t]=0.f; acc3[t]=0.f; }
    for (int k = 0; k < 2*LAT; k += 4){
      float w0 = Wcomb[(size_t)(k+0) * SYM + tid];
      float w1 = Wcomb[(size_t)(k+1) * SYM + tid];
      float w2 = Wcomb[(size_t)(k+2) * SYM + tid];
      float w3 = Wcomb[(size_t)(k+3) * SYM + tid];
      #pragma unroll
      for (int t = 0; t < RT; ++t){
        float4 av = *(const float4*)&a[t][k];
        acc0[t] += av.x * w0; acc1[t] += av.y * w1;
        acc2[t] += av.z * w2; acc3[t] += av.w * w3;
      }
    }
    #pragma unroll
    for (int t = 0; t < RT; ++t)
      raw[t][tid] = rb[tid] + ((acc0[t] + acc1[t]) + (acc2[t] + acc3[t]));
    __syncthreads();
    float bv[RT]; int bi[RT];
    #pragma unroll
    for (int t = 0; t < RT; ++t){ bv[t] = INFINITY; bi[t] = 0x7fffffff; }
    #pragma unroll
    for (int cc = 0; cc < 2; ++cc){
      int c = tid + cc * 256;
      const float* cr = cb + (size_t)c * SYM;
      float d[RT] = {};
      for (int j = 0; j < SYM; j += 4){
        float4 cv = *(const float4*)(cr + j);
        #pragma unroll
        for (int t = 0; t < RT; ++t){
          float4 rv4 = *(const float4*)&raw[t][j];
          d[t] += rv4.x*cv.x + rv4.y*cv.y + rv4.z*cv.z + rv4.w*cv.w;
        }
      }
      #pragma unroll
      for (int t = 0; t < RT; ++t){
        float s = cnorm[c] - 2.f * d[t];
        if (s < bv[t] || (s == bv[t] && c < bi[t])){ bv[t] = s; bi[t] = c; }
      }
    }
    #pragma unroll
    for (int t = 0; t < RT; ++t){
      float v = bv[t]; int i = bi[t];
      #pragma unroll
      for (int off = 32; off; off >>= 1){
        float ov = __shfl_down(v, off, 64);
        int   oi = __shfl_down(i, off, 64);
        if (ov < v || (ov == v && oi < i)){ v = ov; i = oi; }
      }
      if (lane == 0){ pv[t][wave] = v; pi[t][wave] = i; }
    }
    __syncthreads();
    if (tid < nt){
      float v = pv[tid][0]; int i = pi[tid][0];
      #pragma unroll
      for (int w = 1; w < 4; ++w){
        if (pv[tid][w] < v || (pv[tid][w] == v && pi[tid][w] < i)){ v = pv[tid][w]; i = pi[tid][w]; }
      }
      fidx[tid] = i;
      out_idx[rlist[base + tid]] = (float)i;
    }
    __syncthreads();
    for (int t = 0; t < nt; ++t){
      int m = rlist[base + t];
      int idx = fidx[t];
      float cvv = cb[(size_t)idx * SYM + tid];
      out_q[(size_t)m * SYM + tid] = cvv;
      q_h[(size_t)m * SYM + tid] = f2bf(cvv);
    }
    __syncthreads();   // protect a/raw/fidx reuse across chunks
  }
}

} // namespace

extern "C" void kernel_launch(void* const* d_in, const int* in_sizes, int n_in,
                              void* d_out, int out_size, void* d_ws, size_t ws_size,
                              hipStream_t stream){
  const float* token_state = (const float*)d_in[0];
  const float* bus_symbols = (const float*)d_in[1];
  const float* bus_outputs = (const float*)d_in[3];
  const float* Wq    = (const float*)d_in[5];
  const float* Wread = (const float*)d_in[7];
  const float* bread = (const float*)d_in[8];
  const float* Wsym  = (const float*)d_in[9];
  const float* bsym  = (const float*)d_in[10];
  const float* Wc1   = (const float*)d_in[11];
  const float* bc1   = (const float*)d_in[12];
  const float* Wc2   = (const float*)d_in[13];
  const float* bc2   = (const float*)d_in[14];
  const float* codebook = (const float*)d_in[15];

  float* out_node = (float*)d_out;                       // [NTOK*LAT]
  float* out_quant= out_node + (size_t)NTOK * LAT;       // [NTOK*SYM]
  float* out_idx  = out_quant + (size_t)NTOK * SYM;      // [NTOK]
  float* out_mask = out_idx + NTOK;                      // [T]

  // ---- workspace layout (256B aligned) ----
  char* W = (char*)d_ws; size_t off = 0;
  auto alloc = [&](size_t bytes)->char*{ char* p = W + off; off = (off + bytes + 255) & ~(size_t)255; return p; };
  int*   top     = (int*)alloc(NTOK*4);
  char*  zeroed  = alloc(256);              // counts (32B) + rcount (@128), one memset
  int*   counts  = (int*)zeroed;
  int*   rcount  = (int*)(zeroed + 128);
  int*   rlist   = (int*)alloc(NTOK*4);
  float* cbT     = (float*)alloc((size_t)SYM*NC*4);
  float* cnorm   = (float*)alloc(NC*4);
  float* svec    = (float*)alloc(NC*4);
  float* rb      = (float*)alloc(SYM*4);
  float* Wcomb   = (float*)alloc((size_t)2*LAT*SYM*4);
  unsigned short* WreadT = (unsigned short*)alloc((size_t)LAT*2*LAT*2);
  unsigned short* Wc1T   = (unsigned short*)alloc((size_t)LAT*(LAT+SYM)*2);
  unsigned short* Wc2T   = (unsigned short*)alloc((size_t)LAT*LAT*2);
  unsigned short* WfuseT = (unsigned short*)alloc((size_t)NC*LAT*2);
  unsigned short* z_h    = (unsigned short*)alloc((size_t)NTOK*LAT*2);
  unsigned short* q_h    = (unsigned short*)alloc((size_t)NTOK*SYM*2);
  unsigned short* h_h    = (unsigned short*)alloc((size_t)NTOK*LAT*2);
  char* az_region        = alloc((size_t)NTOK*2*LAT*2);     // A_z bf16 (32MB)
  unsigned short* A_z    = (unsigned short*)az_region;
  float* scores          = (float*)az_region;               // overlay: A_z dead before scores written

  hipMemsetAsync(zeroed, 0, 256, stream);

  route_k<<<NTOK/4, 256, 0, stream>>>(bus_symbols, Wq, top, counts);
  cbt_k<<<(NC*SYM)/256, 256, 0, stream>>>(codebook, cbT, counts, out_mask);
  cnorm_k<<<NC/4 + 1, 256, 0, stream>>>(codebook, bsym, cnorm, svec, bread, Wsym, rb);

  // WfuseT = bf16((Wsym @ cbT)^T)  [NC x LAT], fused transpose epilogue
  gemm_f32<64,64,8,4,4,1><<<dim3(LAT/64, NC/64), 256, 0, stream>>>(
      Wsym, cbT, nullptr, WfuseT, LAT, NC, SYM);
  // Wcomb = Wread @ Wsym  [2LAT x SYM] f32 (repair path); 32-row tiles -> 256 blocks
  gemm_f32<32,64,8,2,4,0><<<dim3(2*LAT/32, SYM/64), 256, 0, stream>>>(
      Wread, Wsym, Wcomb, nullptr, 2*LAT, SYM, LAT);
  // all three weight transposes in one dispatch
  t32multi_k<<<2048+1280+1024, 256, 0, stream>>>(Wread, WreadT, Wc1, Wc1T, Wc2, Wc2T);

  pack_az<<<(NTOK*512)/256, 256, 0, stream>>>(token_state, bus_outputs, top, A_z);

  // z_h = bf16(A_z @ WreadT^T + bread)   [NTOK x LAT]
  mgemm<A_PLAIN, EP_ZH><<<dim3(LAT/128, NTOK/128), 256, 0, stream>>>(
      A_z, nullptr, WreadT, bread, nullptr, z_h, nullptr, LAT, 2*LAT, 0);
  // scores = svec - 2 * z_h @ WfuseT^T   [NTOK x NC] f32 (overlay on A_z)
  mgemm<A_PLAIN, EP_VQ><<<dim3(NC/128, NTOK/128), 256, 0, stream>>>(
      z_h, nullptr, WfuseT, svec, nullptr, nullptr, scores, NC, LAT, 0);

  vq_k<<<NTOK/4, 256, 0, stream>>>(scores, codebook, out_quant, out_idx, q_h, rcount, rlist);
  repair_k<<<512, 256, 0, stream>>>(rcount, rlist, top, token_state, bus_outputs,
                                    Wcomb, rb, codebook, cnorm, out_quant, out_idx, q_h);

  // h_h = bf16(relu([z_h | q_h] @ Wc1T^T + bc1))
  mgemm<A_CAT, EP_RELU><<<dim3(LAT/128, NTOK/128), 256, 0, stream>>>(
      z_h, q_h, Wc1T, bc1, nullptr, h_h, nullptr, LAT, LAT+SYM, LAT);
  // out_node = h_h @ Wc2T^T + bc2 + token_state   (f32)
  mgemm<A_PLAIN, EP_OUT><<<dim3(LAT/128, NTOK/128), 256, 0, stream>>>(
      h_h, nullptr, Wc2T, bc2, token_state, nullptr, out_node, LAT, LAT, 0);
}

// Round 6
// 797.853 us; speedup vs baseline: 1.2113x; 1.1354x over previous
//
#include <hip/hip_runtime.h>
#include <hip/hip_bf16.h>

#define DEVI __device__ __forceinline__

namespace {

constexpr int T_   = 8;
constexpr int NTOK = 8192;    // B*S
constexpr int LAT  = 1024;
constexpr int SYM  = 256;
constexpr int NC   = 512;
constexpr float TAU = 0.6f;   // repair margin (approx-score error sigma ~0.07)

typedef short short8 __attribute__((ext_vector_type(8)));
typedef float floatx4 __attribute__((ext_vector_type(4)));

DEVI unsigned short f2bf(float f){
  union { float f; unsigned u; } v; v.f = f;
  return (unsigned short)((v.u + 0x7fffu + ((v.u >> 16) & 1u)) >> 16);
}

// async global->LDS, 16B per lane; LDS dest must be wave-uniform base + lane*16
DEVI void gload_lds16(const void* g, void* l){
  __builtin_amdgcn_global_load_lds((const __attribute__((address_space(1))) void*)g,
                                   (__attribute__((address_space(3))) void*)l, 16, 0, 0);
}

// ---------------- routing + A_z pack: one wave per token --------------------
__global__ void routepack_k(const float* __restrict__ syms, const float* __restrict__ Wq,
                            const float* __restrict__ ts, const float* __restrict__ bus,
                            int* __restrict__ top, int* __restrict__ counts,
                            unsigned short* __restrict__ Az){
  int gt = blockIdx.x * blockDim.x + threadIdx.x;
  int wid = gt >> 6, lane = gt & 63;
  float4 wq = *(const float4*)(Wq + lane * 4);
  float best = -INFINITY; int bt = 0;
  for (int t = 0; t < T_; ++t){
    float4 s = *(const float4*)(syms + ((size_t)t * NTOK + wid) * SYM + lane * 4);
    float p = s.x*wq.x + s.y*wq.y + s.z*wq.z + s.w*wq.w;
    #pragma unroll
    for (int off = 32; off; off >>= 1) p += __shfl_down(p, off, 64);
    p = __shfl(p, 0, 64);
    if (p > best){ best = p; bt = t; }
  }
  if (lane == 0){ top[wid] = bt; atomicAdd(&counts[bt], 1); }
  // pack A_z row for this token (bt uniform across the wave)
  const float* tsrow  = ts  + (size_t)wid * LAT;
  const float* busrow = bus + ((size_t)bt * NTOK + wid) * LAT;
  unsigned short* az  = Az + (size_t)wid * (2*LAT);
  #pragma unroll
  for (int i = 0; i < 4; ++i){
    int c = (i*64 + lane) * 4;
    float4 v = *(const float4*)(tsrow + c);
    ushort4 o; o.x = f2bf(v.x); o.y = f2bf(v.y); o.z = f2bf(v.z); o.w = f2bf(v.w);
    *(ushort4*)(az + c) = o;
    float4 w = *(const float4*)(busrow + c);
    ushort4 p2; p2.x = f2bf(w.x); p2.y = f2bf(w.y); p2.z = f2bf(w.z); p2.w = f2bf(w.w);
    *(ushort4*)(az + LAT + c) = p2;
  }
}

// ---------------- megaprep: all weight-prep work in ONE dispatch ------------
// block ranges:
//   [0,128)      WfuseT gemm  (Wsym @ cb^T, 64x64 tiles, transposed-bf16 out)
//   [128,384)    Wcomb gemm   (Wread @ Wsym, 32x64 tiles, f32 out)
//   [384,4736)   t32 transposes (Wread->WreadT, Wc1->Wc1T, Wc2->Wc2T)
//   [4736,4864)  cnorm/svec
//   [4864]       rbias
constexpr int MP_WFUSE = 128, MP_WCOMB = 384, MP_T32 = 4736, MP_CNORM = 4864;

DEVI void dev_wfuse(int tb, int tid, float* smem,
                    const float* __restrict__ Wsym, const float* __restrict__ cb,
                    unsigned short* __restrict__ WfuseT){
  // M=LAT, K=SYM, N=NC; BM=BN=64, BK=8, TM=TN=4 (256 thr). B[k][n] = cb[n][k].
  float (*As)[68] = (float(*)[68])smem;
  float (*Bs)[68] = (float(*)[68])(smem + 544);
  const int bxm = tb & 15, byn = tb >> 4;          // 16 x 8
  const int m0 = bxm * 64, n0 = byn * 64;
  const int tx = tid & 15, ty = tid >> 4;
  float acc[4][4] = {};
  for (int k0 = 0; k0 < SYM; k0 += 8){
    if (tid < 128){
      int m = tid >> 1, kq = (tid & 1) * 4;
      float4 v = *(const float4*)(Wsym + (size_t)(m0+m) * SYM + k0 + kq);
      As[kq+0][m] = v.x; As[kq+1][m] = v.y; As[kq+2][m] = v.z; As[kq+3][m] = v.w;
    }
    { // B stage: 256 items (64 n x 4 k-pairs)
      int n = tid >> 2, kk = (tid & 3) * 2;
      float2 v = *(const float2*)(cb + (size_t)(n0+n) * SYM + k0 + kk);
      Bs[kk+0][n] = v.x; Bs[kk+1][n] = v.y;
    }
    __syncthreads();
    #pragma unroll
    for (int k = 0; k < 8; ++k){
      float a[4], b[4];
      #pragma unroll
      for (int i = 0; i < 4; ++i) a[i] = As[k][ty*4 + i];
      #pragma unroll
      for (int j = 0; j < 4; ++j) b[j] = Bs[k][tx*4 + j];
      #pragma unroll
      for (int i = 0; i < 4; ++i)
        #pragma unroll
        for (int j = 0; j < 4; ++j) acc[i][j] += a[i] * b[j];
    }
    __syncthreads();
  }
  #pragma unroll
  for (int i = 0; i < 4; ++i)
    #pragma unroll
    for (int j = 0; j < 4; ++j)
      WfuseT[(size_t)(n0 + tx*4 + j) * LAT + m0 + ty*4 + i] = f2bf(acc[i][j]);
}

DEVI void dev_wcomb(int tb, int tid, float* smem,
                    const float* __restrict__ Wread, const float* __restrict__ Wsym,
                    float* __restrict__ Wcomb){
  // M=2048, K=1024, N=256; BM=32, BN=64, BK=8, TM=2, TN=4 (256 thr).
  float (*As)[68] = (float(*)[68])smem;
  float (*Bs)[68] = (float(*)[68])(smem + 544);
  const int bxm = tb & 63, byn = tb >> 6;          // 64 x 4
  const int m0 = bxm * 32, n0 = byn * 64;
  const int tx = tid & 15, ty = tid >> 4;
  float acc[2][4] = {};
  for (int k0 = 0; k0 < LAT; k0 += 8){
    if (tid < 64){
      int m = tid >> 1, kq = (tid & 1) * 4;
      float4 v = *(const float4*)(Wread + (size_t)(m0+m) * LAT + k0 + kq);
      As[kq+0][m] = v.x; As[kq+1][m] = v.y; As[kq+2][m] = v.z; As[kq+3][m] = v.w;
    }
    if (tid < 128){
      int k = tid >> 4, n4 = (tid & 15) * 4;
      *(float4*)&Bs[k][n4] = *(const float4*)(Wsym + (size_t)(k0+k) * SYM + n0 + n4);
    }
    __syncthreads();
    #pragma unroll
    for (int k = 0; k < 8; ++k){
      float a[2], b[4];
      #pragma unroll
      for (int i = 0; i < 2; ++i) a[i] = As[k][ty*2 + i];
      #pragma unroll
      for (int j = 0; j < 4; ++j) b[j] = Bs[k][tx*4 + j];
      #pragma unroll
      for (int i = 0; i < 2; ++i)
        #pragma unroll
        for (int j = 0; j < 4; ++j) acc[i][j] += a[i] * b[j];
    }
    __syncthreads();
  }
  #pragma unroll
  for (int i = 0; i < 2; ++i)
    #pragma unroll
    for (int j = 0; j < 4; ++j)
      Wcomb[(size_t)(m0 + ty*2 + i) * SYM + n0 + tx*4 + j] = acc[i][j];
}

DEVI void dev_t32(int t, int tid, float* smem,
                  const float* __restrict__ in, unsigned short* __restrict__ out,
                  int R, int C){
  float (*tile)[33] = (float(*)[33])smem;
  int bx = t % 32, by = t / 32;
  int r0 = by * 32, c0 = bx * 32;
  int tx = tid & 31, ty = tid >> 5;
  #pragma unroll
  for (int j = 0; j < 4; ++j)
    tile[ty + j*8][tx] = in[(size_t)(r0 + ty + j*8) * C + c0 + tx];
  __syncthreads();
  #pragma unroll
  for (int j = 0; j < 4; ++j)
    out[(size_t)(c0 + ty + j*8) * R + r0 + tx] = f2bf(tile[tx][ty + j*8]);
}

DEVI void dev_cnorm(int lb, int tid, const float* __restrict__ cb,
                    const float* __restrict__ bsym,
                    float* __restrict__ cnorm, float* __restrict__ svec){
  int wid = lb * 4 + (tid >> 6), lane = tid & 63;
  float4 v = *(const float4*)(cb + (size_t)wid * SYM + lane * 4);
  float4 b = *(const float4*)(bsym + lane * 4);
  float p = v.x*v.x + v.y*v.y + v.z*v.z + v.w*v.w;
  float q = v.x*(v.x-2.f*b.x) + v.y*(v.y-2.f*b.y) + v.z*(v.z-2.f*b.z) + v.w*(v.w-2.f*b.w);
  #pragma unroll
  for (int off = 32; off; off >>= 1){ p += __shfl_down(p, off, 64); q += __shfl_down(q, off, 64); }
  if (lane == 0){ cnorm[wid] = p; svec[wid] = q; }
}

DEVI void dev_rbias(int tid, const float* __restrict__ bread,
                    const float* __restrict__ Wsym, const float* __restrict__ bsym,
                    float* __restrict__ rb){
  float a0=0.f,a1=0.f,a2=0.f,a3=0.f;
  for (int k = 0; k < LAT; k += 4){
    a0 += bread[k+0] * Wsym[(size_t)(k+0) * SYM + tid];
    a1 += bread[k+1] * Wsym[(size_t)(k+1) * SYM + tid];
    a2 += bread[k+2] * Wsym[(size_t)(k+2) * SYM + tid];
    a3 += bread[k+3] * Wsym[(size_t)(k+3) * SYM + tid];
  }
  rb[tid] = bsym[tid] + ((a0+a1)+(a2+a3));
}

__global__ __launch_bounds__(256)
void megaprep_k(const float* __restrict__ Wsym, const float* __restrict__ cb,
                unsigned short* __restrict__ WfuseT,
                const float* __restrict__ Wread, float* __restrict__ Wcomb,
                unsigned short* __restrict__ WreadT,
                const float* __restrict__ Wc1, unsigned short* __restrict__ Wc1T,
                const float* __restrict__ Wc2, unsigned short* __restrict__ Wc2T,
                const float* __restrict__ bsym, float* __restrict__ cnorm,
                float* __restrict__ svec,
                const float* __restrict__ bread, float* __restrict__ rb){
  __shared__ float smem[1088];
  int b = blockIdx.x, tid = threadIdx.x;
  if (b < MP_WFUSE){
    dev_wfuse(b, tid, smem, Wsym, cb, WfuseT);
  } else if (b < MP_WCOMB){
    dev_wcomb(b - MP_WFUSE, tid, smem, Wread, Wsym, Wcomb);
  } else if (b < MP_T32){
    int t = b - MP_WCOMB;
    if (t < 2048)      dev_t32(t,        tid, smem, Wread, WreadT, 2*LAT, LAT);
    else if (t < 3328) dev_t32(t - 2048, tid, smem, Wc1,   Wc1T,   LAT+SYM, LAT);
    else               dev_t32(t - 3328, tid, smem, Wc2,   Wc2T,   LAT,  LAT);
  } else if (b < MP_CNORM){
    dev_cnorm(b - MP_T32, tid, cb, bsym, cnorm, svec);
  } else {
    dev_rbias(tid, bread, Wsym, bsym, rb);
  }
}

// ---------------- MFMA bf16 GEMM: C = A @ BT^T ------------------------------
// A [M x K] bf16 RM (CAT: A stride asplit, A2 stride K-asplit), BT [N x K] bf16 RM.
// 128x128 tile, BK=32, 4 waves (2x2), each wave 64x64 = 4x4 mfma_16x16x32.
// Staging via global_load_lds width=16; LDS linear both sides.
// XCD-aware bijective block swizzle (nwg % 8 == 0 at all call sites).
constexpr int A_PLAIN = 0, A_CAT = 1;
constexpr int EP_ZH = 0, EP_VQ = 1, EP_RELU = 2, EP_OUT = 3;

template<int ASRC, int EPI>
__global__ __launch_bounds__(256)
void mgemm(const unsigned short* __restrict__ A, const unsigned short* __restrict__ A2,
           const unsigned short* __restrict__ BT, const float* __restrict__ bias,
           const float* __restrict__ resid,
           unsigned short* __restrict__ Cb, float* __restrict__ Cf,
           int N, int K, int asplit)
{
  __shared__ unsigned short As[128*32];
  __shared__ unsigned short Bs[128*32];
  const int tid  = threadIdx.x;
  const int wave = tid >> 6, lane = tid & 63;
  const int wy = wave >> 1, wx = wave & 1;
  const int lq = lane >> 4, lr = lane & 15;

  const int nwg  = gridDim.x * gridDim.y;
  const int orig = blockIdx.y * gridDim.x + blockIdx.x;
  const int dec  = (orig & 7) * (nwg >> 3) + (orig >> 3);
  const int bx   = dec % gridDim.x, by = dec / gridDim.x;
  const int m0 = by * 128, n0 = bx * 128;

  floatx4 acc[4][4] = {};

  for (int k0 = 0; k0 < K; k0 += 32){
    #pragma unroll
    for (int c = 0; c < 2; ++c){
      int chunk = tid + c*256;                 // 0..511
      int mrel = chunk >> 2, kc = (chunk & 3) * 8;
      int gk = k0 + kc;
      const unsigned short* srcA;
      if constexpr (ASRC == A_CAT){
        if (gk < asplit) srcA = A  + (size_t)(m0+mrel) * asplit + gk;
        else             srcA = A2 + (size_t)(m0+mrel) * (K-asplit) + (gk-asplit);
      } else {
        srcA = A + (size_t)(m0+mrel) * K + gk;
      }
      gload_lds16(srcA, &As[(c*256 + wave*64) * 8]);
      gload_lds16(BT + (size_t)(n0+mrel) * K + gk, &Bs[(c*256 + wave*64) * 8]);
    }
    __syncthreads();
    short8 af[4], bf[4];
    #pragma unroll
    for (int i = 0; i < 4; ++i){
      af[i] = *(const short8*)&As[(wy*64 + i*16 + lr)*32 + lq*8];
      bf[i] = *(const short8*)&Bs[(wx*64 + i*16 + lr)*32 + lq*8];
    }
    #pragma unroll
    for (int i = 0; i < 4; ++i)
      #pragma unroll
      for (int j = 0; j < 4; ++j)
        acc[i][j] = __builtin_amdgcn_mfma_f32_16x16x32_bf16(af[i], bf[j], acc[i][j], 0, 0, 0);
    __syncthreads();
  }

  #pragma unroll
  for (int i = 0; i < 4; ++i){
    #pragma unroll
    for (int j = 0; j < 4; ++j){
      int gn = n0 + wx*64 + j*16 + lr;
      #pragma unroll
      for (int r = 0; r < 4; ++r){
        int gm = m0 + wy*64 + i*16 + lq*4 + r;
        float v = acc[i][j][r];
        if constexpr (EPI == EP_ZH){
          Cb[(size_t)gm * N + gn] = f2bf(v + bias[gn]);
        } else if constexpr (EPI == EP_VQ){
          Cf[(size_t)gm * N + gn] = bias[gn] - 2.f * v;     // bias = svec
        } else if constexpr (EPI == EP_RELU){
          float u = v + bias[gn];
          Cb[(size_t)gm * N + gn] = f2bf(u > 0.f ? u : 0.f);
        } else {
          Cf[(size_t)gm * N + gn] = v + bias[gn] + resid[(size_t)gm * N + gn];
        }
      }
    }
  }
}

// ---------------- VQ: top-2 margin argmin + gather + repair flagging --------
// (also writes keep-mask in block 0 — counts are final after routepack_k)
__global__ void vq_k(const float* __restrict__ scores, const float* __restrict__ cb,
                     float* __restrict__ out_q, float* __restrict__ out_idx,
                     unsigned short* __restrict__ q_h,
                     int* __restrict__ rcount, int* __restrict__ rlist,
                     const int* __restrict__ counts, float* __restrict__ out_mask){
  if (blockIdx.x == 0 && threadIdx.x < T_)
    out_mask[threadIdx.x] = (counts[threadIdx.x] == 0) ? 1.0f : 0.0f;
  int gt = blockIdx.x * blockDim.x + threadIdx.x;
  int wid = gt >> 6, lane = gt & 63;
  if (wid >= NTOK) return;
  const float* row = scores + (size_t)wid * NC;
  float v1 = INFINITY, v2 = INFINITY; int i1 = 0x7fffffff;
  #pragma unroll
  for (int i = 0; i < NC/64; ++i){
    int c = i*64 + lane;
    float v = row[c];
    if (v < v1){ v2 = v1; v1 = v; i1 = c; } else v2 = fminf(v2, v);
  }
  #pragma unroll
  for (int off = 32; off; off >>= 1){
    float ov1 = __shfl_down(v1, off, 64);
    int   oi1 = __shfl_down(i1, off, 64);
    float ov2 = __shfl_down(v2, off, 64);
    float rest;
    if (ov1 < v1 || (ov1 == v1 && oi1 < i1)){ rest = v1; v1 = ov1; i1 = oi1; }
    else rest = ov1;
    v2 = fminf(fminf(v2, ov2), rest);
  }
  i1 = __shfl(i1, 0, 64);
  if (lane == 0){
    out_idx[wid] = (float)i1;
    if (__shfl(v2, 0, 64) - __shfl(v1, 0, 64) < TAU){
      int p = atomicAdd(rcount, 1); rlist[p] = wid;
    }
  }
  float4 cv = *(const float4*)(cb + (size_t)i1 * SYM + lane * 4);
  *(float4*)(out_q + (size_t)wid * SYM + lane * 4) = cv;
  ushort4 qh; qh.x = f2bf(cv.x); qh.y = f2bf(cv.y); qh.z = f2bf(cv.z); qh.w = f2bf(cv.w);
  *(ushort4*)(q_h + (size_t)wid * SYM + lane * 4) = qh;
}

// ---------------- exact f32 repair for near-tie tokens ----------------------
constexpr int RT = 4;

__global__ __launch_bounds__(256)
void repair_k(const int* __restrict__ rcount, const int* __restrict__ rlist,
              const int* __restrict__ top,
              const float* __restrict__ ts, const float* __restrict__ bus,
              const float* __restrict__ Wcomb, const float* __restrict__ rb,
              const float* __restrict__ cb, const float* __restrict__ cnorm,
              float* __restrict__ out_q, float* __restrict__ out_idx,
              unsigned short* __restrict__ q_h){
  __shared__ float a[RT][2*LAT];       // 32 KB
  __shared__ float raw[RT][SYM];       // 4 KB
  __shared__ float pv[RT][4];
  __shared__ int   pi[RT][4];
  __shared__ int   fidx[RT];
  int tid = threadIdx.x;
  int lane = tid & 63, wave = tid >> 6;
  int cnt = *rcount;
  int nchunk = (cnt + RT - 1) / RT;
  for (int ch = blockIdx.x; ch < nchunk; ch += gridDim.x){
    int base = ch * RT;
    int nt = min(RT, cnt - base);
    for (int q = tid; q < nt * 512; q += 256){
      int t = q >> 9, c = (q & 511) * 4;
      int m = rlist[base + t];
      int tp = top[m];
      float4 v = (c < LAT) ? *(const float4*)(ts + (size_t)m * LAT + c)
                           : *(const float4*)(bus + ((size_t)tp * NTOK + m) * LAT + (c - LAT));
      *(float4*)&a[t][c] = v;
    }
    __syncthreads();
    float acc0[RT], acc1[RT], acc2[RT], acc3[RT];
    #pragma unroll
    for (int t = 0; t < RT; ++t){ acc0[t]=0.f; acc1[t]=0.f; acc2[t]=0.f; acc3[t]=0.f; }
    for (int k = 0; k < 2*LAT; k += 4){
      float w0 = Wcomb[(size_t)(k+0) * SYM + tid];
      float w1 = Wcomb[(size_t)(k+1) * SYM + tid];
      float w2 = Wcomb[(size_t)(k+2) * SYM + tid];
      float w3 = Wcomb[(size_t)(k+3) * SYM + tid];
      #pragma unroll
      for (int t = 0; t < RT; ++t){
        float4 av = *(const float4*)&a[t][k];
        acc0[t] += av.x * w0; acc1[t] += av.y * w1;
        acc2[t] += av.z * w2; acc3[t] += av.w * w3;
      }
    }
    #pragma unroll
    for (int t = 0; t < RT; ++t)
      raw[t][tid] = rb[tid] + ((acc0[t] + acc1[t]) + (acc2[t] + acc3[t]));
    __syncthreads();
    float bv[RT]; int bi[RT];
    #pragma unroll
    for (int t = 0; t < RT; ++t){ bv[t] = INFINITY; bi[t] = 0x7fffffff; }
    #pragma unroll
    for (int cc = 0; cc < 2; ++cc){
      int c = tid + cc * 256;
      const float* cr = cb + (size_t)c * SYM;
      float d[RT] = {};
      for (int j = 0; j < SYM; j += 4){
        float4 cv = *(const float4*)(cr + j);
        #pragma unroll
        for (int t = 0; t < RT; ++t){
          float4 rv4 = *(const float4*)&raw[t][j];
          d[t] += rv4.x*cv.x + rv4.y*cv.y + rv4.z*cv.z + rv4.w*cv.w;
        }
      }
      #pragma unroll
      for (int t = 0; t < RT; ++t){
        float s = cnorm[c] - 2.f * d[t];
        if (s < bv[t] || (s == bv[t] && c < bi[t])){ bv[t] = s; bi[t] = c; }
      }
    }
    #pragma unroll
    for (int t = 0; t < RT; ++t){
      float v = bv[t]; int i = bi[t];
      #pragma unroll
      for (int off = 32; off; off >>= 1){
        float ov = __shfl_down(v, off, 64);
        int   oi = __shfl_down(i, off, 64);
        if (ov < v || (ov == v && oi < i)){ v = ov; i = oi; }
      }
      if (lane == 0){ pv[t][wave] = v; pi[t][wave] = i; }
    }
    __syncthreads();
    if (tid < nt){
      float v = pv[tid][0]; int i = pi[tid][0];
      #pragma unroll
      for (int w = 1; w < 4; ++w){
        if (pv[tid][w] < v || (pv[tid][w] == v && pi[tid][w] < i)){ v = pv[tid][w]; i = pi[tid][w]; }
      }
      fidx[tid] = i;
      out_idx[rlist[base + tid]] = (float)i;
    }
    __syncthreads();
    for (int t = 0; t < nt; ++t){
      int m = rlist[base + t];
      int idx = fidx[t];
      float cvv = cb[(size_t)idx * SYM + tid];
      out_q[(size_t)m * SYM + tid] = cvv;
      q_h[(size_t)m * SYM + tid] = f2bf(cvv);
    }
    __syncthreads();   // protect a/raw/fidx reuse across chunks
  }
}

} // namespace

extern "C" void kernel_launch(void* const* d_in, const int* in_sizes, int n_in,
                              void* d_out, int out_size, void* d_ws, size_t ws_size,
                              hipStream_t stream){
  const float* token_state = (const float*)d_in[0];
  const float* bus_symbols = (const float*)d_in[1];
  const float* bus_outputs = (const float*)d_in[3];
  const float* Wq    = (const float*)d_in[5];
  const float* Wread = (const float*)d_in[7];
  const float* bread = (const float*)d_in[8];
  const float* Wsym  = (const float*)d_in[9];
  const float* bsym  = (const float*)d_in[10];
  const float* Wc1   = (const float*)d_in[11];
  const float* bc1   = (const float*)d_in[12];
  const float* Wc2   = (const float*)d_in[13];
  const float* bc2   = (const float*)d_in[14];
  const float* codebook = (const float*)d_in[15];

  float* out_node = (float*)d_out;                       // [NTOK*LAT]
  float* out_quant= out_node + (size_t)NTOK * LAT;       // [NTOK*SYM]
  float* out_idx  = out_quant + (size_t)NTOK * SYM;      // [NTOK]
  float* out_mask = out_idx + NTOK;                      // [T]

  // ---- workspace layout (256B aligned) ----
  char* W = (char*)d_ws; size_t off = 0;
  auto alloc = [&](size_t bytes)->char*{ char* p = W + off; off = (off + bytes + 255) & ~(size_t)255; return p; };
  int*   top     = (int*)alloc(NTOK*4);
  char*  zeroed  = alloc(256);              // counts (32B) + rcount (@128), one memset
  int*   counts  = (int*)zeroed;
  int*   rcount  = (int*)(zeroed + 128);
  int*   rlist   = (int*)alloc(NTOK*4);
  float* cnorm   = (float*)alloc(NC*4);
  float* svec    = (float*)alloc(NC*4);
  float* rb      = (float*)alloc(SYM*4);
  float* Wcomb   = (float*)alloc((size_t)2*LAT*SYM*4);
  unsigned short* WreadT = (unsigned short*)alloc((size_t)LAT*2*LAT*2);
  unsigned short* Wc1T   = (unsigned short*)alloc((size_t)LAT*(LAT+SYM)*2);
  unsigned short* Wc2T   = (unsigned short*)alloc((size_t)LAT*LAT*2);
  unsigned short* WfuseT = (unsigned short*)alloc((size_t)NC*LAT*2);
  unsigned short* z_h    = (unsigned short*)alloc((size_t)NTOK*LAT*2);
  unsigned short* q_h    = (unsigned short*)alloc((size_t)NTOK*SYM*2);
  unsigned short* h_h    = (unsigned short*)alloc((size_t)NTOK*LAT*2);
  char* az_region        = alloc((size_t)NTOK*2*LAT*2);     // A_z bf16 (32MB)
  unsigned short* A_z    = (unsigned short*)az_region;
  float* scores          = (float*)az_region;               // overlay: A_z dead before scores written

  hipMemsetAsync(zeroed, 0, 256, stream);

  // routing + A_z pack (one wave per token)
  routepack_k<<<NTOK/4, 256, 0, stream>>>(bus_symbols, Wq, token_state, bus_outputs,
                                          top, counts, A_z);
  // all weight prep in one dispatch
  megaprep_k<<<MP_CNORM + 1, 256, 0, stream>>>(
      Wsym, codebook, WfuseT, Wread, Wcomb, WreadT, Wc1, Wc1T, Wc2, Wc2T,
      bsym, cnorm, svec, bread, rb);

  // z_h = bf16(A_z @ WreadT^T + bread)   [NTOK x LAT]
  mgemm<A_PLAIN, EP_ZH><<<dim3(LAT/128, NTOK/128), 256, 0, stream>>>(
      A_z, nullptr, WreadT, bread, nullptr, z_h, nullptr, LAT, 2*LAT, 0);
  // scores = svec - 2 * z_h @ WfuseT^T   [NTOK x NC] f32 (overlay on A_z)
  mgemm<A_PLAIN, EP_VQ><<<dim3(NC/128, NTOK/128), 256, 0, stream>>>(
      z_h, nullptr, WfuseT, svec, nullptr, nullptr, scores, NC, LAT, 0);

  vq_k<<<NTOK/4, 256, 0, stream>>>(scores, codebook, out_quant, out_idx, q_h,
                                   rcount, rlist, counts, out_mask);
  repair_k<<<512, 256, 0, stream>>>(rcount, rlist, top, token_state, bus_outputs,
                                    Wcomb, rb, codebook, cnorm, out_quant, out_idx, q_h);

  // h_h = bf16(relu([z_h | q_h] @ Wc1T^T + bc1))
  mgemm<A_CAT, EP_RELU><<<dim3(LAT/128, NTOK/128), 256, 0, stream>>>(
      z_h, q_h, Wc1T, bc1, nullptr, h_h, nullptr, LAT, LAT+SYM, LAT);
  // out_node = h_h @ Wc2T^T + bc2 + token_state   (f32)
  mgemm<A_PLAIN, EP_OUT><<<dim3(LAT/128, NTOK/128), 256, 0, stream>>>(
      h_h, nullptr, Wc2T, bc2, token_state, nullptr, out_node, LAT, LAT, 0);
}

// Round 8
// 778.776 us; speedup vs baseline: 1.2410x; 1.0245x over previous
//
#include <hip/hip_runtime.h>
#include <hip/hip_bf16.h>

#define DEVI __device__ __forceinline__

namespace {

constexpr int T_   = 8;
constexpr int NTOK = 8192;    // B*S
constexpr int LAT  = 1024;
constexpr int SYM  = 256;
constexpr int NC   = 512;
constexpr float TAU = 0.6f;   // repair margin (approx-score error sigma ~0.07)

typedef short short8 __attribute__((ext_vector_type(8)));
typedef float floatx4 __attribute__((ext_vector_type(4)));

DEVI unsigned short f2bf(float f){
  union { float f; unsigned u; } v; v.f = f;
  return (unsigned short)((v.u + 0x7fffu + ((v.u >> 16) & 1u)) >> 16);
}

// async global->LDS, 16B per lane; LDS dest must be wave-uniform base + lane*16
DEVI void gload_lds16(const void* g, void* l){
  __builtin_amdgcn_global_load_lds((const __attribute__((address_space(1))) void*)g,
                                   (__attribute__((address_space(3))) void*)l, 16, 0, 0);
}

// ---------------- routing + A_z pack: one wave per token --------------------
// also zeroes rcount (block 0) so no memset dispatch is needed.
__global__ void routepack_k(const float* __restrict__ syms, const float* __restrict__ Wq,
                            const float* __restrict__ ts, const float* __restrict__ bus,
                            int* __restrict__ top, int* __restrict__ rcount,
                            unsigned short* __restrict__ Az){
  if (blockIdx.x == 0 && threadIdx.x == 0) *rcount = 0;
  int gt = blockIdx.x * blockDim.x + threadIdx.x;
  int wid = gt >> 6, lane = gt & 63;
  float4 wq = *(const float4*)(Wq + lane * 4);
  float best = -INFINITY; int bt = 0;
  for (int t = 0; t < T_; ++t){
    float4 s = *(const float4*)(syms + ((size_t)t * NTOK + wid) * SYM + lane * 4);
    float p = s.x*wq.x + s.y*wq.y + s.z*wq.z + s.w*wq.w;
    #pragma unroll
    for (int off = 32; off; off >>= 1) p += __shfl_down(p, off, 64);
    p = __shfl(p, 0, 64);
    if (p > best){ best = p; bt = t; }
  }
  if (lane == 0) top[wid] = bt;
  // pack A_z row for this token (bt uniform across the wave)
  const float* tsrow  = ts  + (size_t)wid * LAT;
  const float* busrow = bus + ((size_t)bt * NTOK + wid) * LAT;
  unsigned short* az  = Az + (size_t)wid * (2*LAT);
  #pragma unroll
  for (int i = 0; i < 4; ++i){
    int c = (i*64 + lane) * 4;
    float4 v = *(const float4*)(tsrow + c);
    ushort4 o; o.x = f2bf(v.x); o.y = f2bf(v.y); o.z = f2bf(v.z); o.w = f2bf(v.w);
    *(ushort4*)(az + c) = o;
    float4 w = *(const float4*)(busrow + c);
    ushort4 p2; p2.x = f2bf(w.x); p2.y = f2bf(w.y); p2.z = f2bf(w.z); p2.w = f2bf(w.w);
    *(ushort4*)(az + LAT + c) = p2;
  }
}

// ---------------- megaprep: all weight-prep work in ONE dispatch ------------
constexpr int MP_WFUSE = 128, MP_WCOMB = 384, MP_T32 = 4736, MP_CNORM = 4864;

DEVI void dev_wfuse(int tb, int tid, float* smem,
                    const float* __restrict__ Wsym, const float* __restrict__ cb,
                    unsigned short* __restrict__ WfuseT){
  // M=LAT, K=SYM, N=NC; BM=BN=64, BK=8, TM=TN=4 (256 thr). B[k][n] = cb[n][k].
  float (*As)[68] = (float(*)[68])smem;
  float (*Bs)[68] = (float(*)[68])(smem + 544);
  const int bxm = tb & 15, byn = tb >> 4;          // 16 x 8
  const int m0 = bxm * 64, n0 = byn * 64;
  const int tx = tid & 15, ty = tid >> 4;
  float acc[4][4] = {};
  for (int k0 = 0; k0 < SYM; k0 += 8){
    if (tid < 128){
      int m = tid >> 1, kq = (tid & 1) * 4;
      float4 v = *(const float4*)(Wsym + (size_t)(m0+m) * SYM + k0 + kq);
      As[kq+0][m] = v.x; As[kq+1][m] = v.y; As[kq+2][m] = v.z; As[kq+3][m] = v.w;
    }
    { // B stage: 256 items (64 n x 4 k-pairs)
      int n = tid >> 2, kk = (tid & 3) * 2;
      float2 v = *(const float2*)(cb + (size_t)(n0+n) * SYM + k0 + kk);
      Bs[kk+0][n] = v.x; Bs[kk+1][n] = v.y;
    }
    __syncthreads();
    #pragma unroll
    for (int k = 0; k < 8; ++k){
      float a[4], b[4];
      #pragma unroll
      for (int i = 0; i < 4; ++i) a[i] = As[k][ty*4 + i];
      #pragma unroll
      for (int j = 0; j < 4; ++j) b[j] = Bs[k][tx*4 + j];
      #pragma unroll
      for (int i = 0; i < 4; ++i)
        #pragma unroll
        for (int j = 0; j < 4; ++j) acc[i][j] += a[i] * b[j];
    }
    __syncthreads();
  }
  #pragma unroll
  for (int i = 0; i < 4; ++i)
    #pragma unroll
    for (int j = 0; j < 4; ++j)
      WfuseT[(size_t)(n0 + tx*4 + j) * LAT + m0 + ty*4 + i] = f2bf(acc[i][j]);
}

DEVI void dev_wcomb(int tb, int tid, float* smem,
                    const float* __restrict__ Wread, const float* __restrict__ Wsym,
                    float* __restrict__ Wcomb){
  // M=2048, K=1024, N=256; BM=32, BN=64, BK=8, TM=2, TN=4 (256 thr).
  float (*As)[68] = (float(*)[68])smem;
  float (*Bs)[68] = (float(*)[68])(smem + 544);
  const int bxm = tb & 63, byn = tb >> 6;          // 64 x 4
  const int m0 = bxm * 32, n0 = byn * 64;
  const int tx = tid & 15, ty = tid >> 4;
  float acc[2][4] = {};
  for (int k0 = 0; k0 < LAT; k0 += 8){
    if (tid < 64){
      int m = tid >> 1, kq = (tid & 1) * 4;
      float4 v = *(const float4*)(Wread + (size_t)(m0+m) * LAT + k0 + kq);
      As[kq+0][m] = v.x; As[kq+1][m] = v.y; As[kq+2][m] = v.z; As[kq+3][m] = v.w;
    }
    if (tid < 128){
      int k = tid >> 4, n4 = (tid & 15) * 4;
      *(float4*)&Bs[k][n4] = *(const float4*)(Wsym + (size_t)(k0+k) * SYM + n0 + n4);
    }
    __syncthreads();
    #pragma unroll
    for (int k = 0; k < 8; ++k){
      float a[2], b[4];
      #pragma unroll
      for (int i = 0; i < 2; ++i) a[i] = As[k][ty*2 + i];
      #pragma unroll
      for (int j = 0; j < 4; ++j) b[j] = Bs[k][tx*4 + j];
      #pragma unroll
      for (int i = 0; i < 2; ++i)
        #pragma unroll
        for (int j = 0; j < 4; ++j) acc[i][j] += a[i] * b[j];
    }
    __syncthreads();
  }
  #pragma unroll
  for (int i = 0; i < 2; ++i)
    #pragma unroll
    for (int j = 0; j < 4; ++j)
      Wcomb[(size_t)(m0 + ty*2 + i) * SYM + n0 + tx*4 + j] = acc[i][j];
}

DEVI void dev_t32(int t, int tid, float* smem,
                  const float* __restrict__ in, unsigned short* __restrict__ out,
                  int R, int C){
  float (*tile)[33] = (float(*)[33])smem;
  int bx = t % 32, by = t / 32;
  int r0 = by * 32, c0 = bx * 32;
  int tx = tid & 31, ty = tid >> 5;
  #pragma unroll
  for (int j = 0; j < 4; ++j)
    tile[ty + j*8][tx] = in[(size_t)(r0 + ty + j*8) * C + c0 + tx];
  __syncthreads();
  #pragma unroll
  for (int j = 0; j < 4; ++j)
    out[(size_t)(c0 + ty + j*8) * R + r0 + tx] = f2bf(tile[tx][ty + j*8]);
}

DEVI void dev_cnorm(int lb, int tid, const float* __restrict__ cb,
                    const float* __restrict__ bsym,
                    float* __restrict__ cnorm, float* __restrict__ svec){
  int wid = lb * 4 + (tid >> 6), lane = tid & 63;
  float4 v = *(const float4*)(cb + (size_t)wid * SYM + lane * 4);
  float4 b = *(const float4*)(bsym + lane * 4);
  float p = v.x*v.x + v.y*v.y + v.z*v.z + v.w*v.w;
  float q = v.x*(v.x-2.f*b.x) + v.y*(v.y-2.f*b.y) + v.z*(v.z-2.f*b.z) + v.w*(v.w-2.f*b.w);
  #pragma unroll
  for (int off = 32; off; off >>= 1){ p += __shfl_down(p, off, 64); q += __shfl_down(q, off, 64); }
  if (lane == 0){ cnorm[wid] = p; svec[wid] = q; }
}

DEVI void dev_rbias(int tid, const float* __restrict__ bread,
                    const float* __restrict__ Wsym, const float* __restrict__ bsym,
                    float* __restrict__ rb){
  float a0=0.f,a1=0.f,a2=0.f,a3=0.f;
  for (int k = 0; k < LAT; k += 4){
    a0 += bread[k+0] * Wsym[(size_t)(k+0) * SYM + tid];
    a1 += bread[k+1] * Wsym[(size_t)(k+1) * SYM + tid];
    a2 += bread[k+2] * Wsym[(size_t)(k+2) * SYM + tid];
    a3 += bread[k+3] * Wsym[(size_t)(k+3) * SYM + tid];
  }
  rb[tid] = bsym[tid] + ((a0+a1)+(a2+a3));
}

__global__ __launch_bounds__(256)
void megaprep_k(const float* __restrict__ Wsym, const float* __restrict__ cb,
                unsigned short* __restrict__ WfuseT,
                const float* __restrict__ Wread, float* __restrict__ Wcomb,
                unsigned short* __restrict__ WreadT,
                const float* __restrict__ Wc1, unsigned short* __restrict__ Wc1T,
                const float* __restrict__ Wc2, unsigned short* __restrict__ Wc2T,
                const float* __restrict__ bsym, float* __restrict__ cnorm,
                float* __restrict__ svec,
                const float* __restrict__ bread, float* __restrict__ rb){
  __shared__ float smem[1088];
  int b = blockIdx.x, tid = threadIdx.x;
  if (b < MP_WFUSE){
    dev_wfuse(b, tid, smem, Wsym, cb, WfuseT);
  } else if (b < MP_WCOMB){
    dev_wcomb(b - MP_WFUSE, tid, smem, Wread, Wsym, Wcomb);
  } else if (b < MP_T32){
    int t = b - MP_WCOMB;
    if (t < 2048)      dev_t32(t,        tid, smem, Wread, WreadT, 2*LAT, LAT);
    else if (t < 3328) dev_t32(t - 2048, tid, smem, Wc1,   Wc1T,   LAT+SYM, LAT);
    else               dev_t32(t - 3328, tid, smem, Wc2,   Wc2T,   LAT,  LAT);
  } else if (b < MP_CNORM){
    dev_cnorm(b - MP_T32, tid, cb, bsym, cnorm, svec);
  } else {
    dev_rbias(tid, bread, Wsym, bsym, rb);
  }
}

// ---------------- MFMA bf16 GEMM: C = A @ BT^T ------------------------------
// 128x128 tile, BK=32, 4 waves (2x2), each wave 64x64 = 4x4 mfma_16x16x32.
// Staging via global_load_lds width=16; LDS linear both sides.
// XCD-aware bijective block swizzle (nwg % 8 == 0 at all call sites).
constexpr int A_PLAIN = 0, A_CAT = 1;
constexpr int EP_ZH = 0, EP_RELU = 2, EP_OUT = 3;

template<int ASRC, int EPI>
__global__ __launch_bounds__(256)
void mgemm(const unsigned short* __restrict__ A, const unsigned short* __restrict__ A2,
           const unsigned short* __restrict__ BT, const float* __restrict__ bias,
           const float* __restrict__ resid,
           unsigned short* __restrict__ Cb, float* __restrict__ Cf,
           int N, int K, int asplit)
{
  __shared__ unsigned short As[128*32];
  __shared__ unsigned short Bs[128*32];
  const int tid  = threadIdx.x;
  const int wave = tid >> 6, lane = tid & 63;
  const int wy = wave >> 1, wx = wave & 1;
  const int lq = lane >> 4, lr = lane & 15;

  const int nwg  = gridDim.x * gridDim.y;
  const int orig = blockIdx.y * gridDim.x + blockIdx.x;
  const int dec  = (orig & 7) * (nwg >> 3) + (orig >> 3);
  const int bx   = dec % gridDim.x, by = dec / gridDim.x;
  const int m0 = by * 128, n0 = bx * 128;

  floatx4 acc[4][4] = {};

  for (int k0 = 0; k0 < K; k0 += 32){
    #pragma unroll
    for (int c = 0; c < 2; ++c){
      int chunk = tid + c*256;                 // 0..511
      int mrel = chunk >> 2, kc = (chunk & 3) * 8;
      int gk = k0 + kc;
      const unsigned short* srcA;
      if constexpr (ASRC == A_CAT){
        if (gk < asplit) srcA = A  + (size_t)(m0+mrel) * asplit + gk;
        else             srcA = A2 + (size_t)(m0+mrel) * (K-asplit) + (gk-asplit);
      } else {
        srcA = A + (size_t)(m0+mrel) * K + gk;
      }
      gload_lds16(srcA, &As[(c*256 + wave*64) * 8]);
      gload_lds16(BT + (size_t)(n0+mrel) * K + gk, &Bs[(c*256 + wave*64) * 8]);
    }
    __syncthreads();
    short8 af[4], bf[4];
    #pragma unroll
    for (int i = 0; i < 4; ++i){
      af[i] = *(const short8*)&As[(wy*64 + i*16 + lr)*32 + lq*8];
      bf[i] = *(const short8*)&Bs[(wx*64 + i*16 + lr)*32 + lq*8];
    }
    #pragma unroll
    for (int i = 0; i < 4; ++i)
      #pragma unroll
      for (int j = 0; j < 4; ++j)
        acc[i][j] = __builtin_amdgcn_mfma_f32_16x16x32_bf16(af[i], bf[j], acc[i][j], 0, 0, 0);
    __syncthreads();
  }

  #pragma unroll
  for (int i = 0; i < 4; ++i){
    #pragma unroll
    for (int j = 0; j < 4; ++j){
      int gn = n0 + wx*64 + j*16 + lr;
      #pragma unroll
      for (int r = 0; r < 4; ++r){
        int gm = m0 + wy*64 + i*16 + lq*4 + r;
        float v = acc[i][j][r];
        if constexpr (EPI == EP_ZH){
          Cb[(size_t)gm * N + gn] = f2bf(v + bias[gn]);
        } else if constexpr (EPI == EP_RELU){
          float u = v + bias[gn];
          Cb[(size_t)gm * N + gn] = f2bf(u > 0.f ? u : 0.f);
        } else {
          Cf[(size_t)gm * N + gn] = v + bias[gn] + resid[(size_t)gm * N + gn];
        }
      }
    }
  }
}

// ---------------- fused VQ GEMM: scores + top-2 argmin + gather + flags -----
// Block: 64 rows x full NC=512 (4 col-chunks of 128). 4 waves 2x2:
// wy = row 32-half, wx = col 64-half; wave tile 32x64 = acc[2][4] per chunk.
// scores s = svec[c] - 2 * (z_h @ WfuseT^T)[m][c] computed identically to the
// old EP_VQ epilogue; per-row top-2 folded in registers (ascending-col scan,
// strict <), shfl_xor butterfly across the 16-lane col group with index
// tie-break, LDS merge across the two col-half waves. Matches vq_k exactly.
__global__ __launch_bounds__(256)
void vqgemm_k(const unsigned short* __restrict__ A /*z_h*/,
              const unsigned short* __restrict__ BT /*WfuseT*/,
              const float* __restrict__ svec, const float* __restrict__ cb,
              const int* __restrict__ top,
              float* __restrict__ out_q, float* __restrict__ out_idx,
              unsigned short* __restrict__ q_h,
              int* __restrict__ rcount, int* __restrict__ rlist,
              float* __restrict__ out_mask)
{
  __shared__ unsigned short As[64*32];
  __shared__ unsigned short Bs[128*32];
  __shared__ float red_v1[64][2]; __shared__ int red_i1[64][2]; __shared__ float red_v2[64][2];
  __shared__ int ridx[64];
  __shared__ int presw[4];
  const int tid = threadIdx.x;
  const int wave = tid >> 6, lane = tid & 63;
  const int wy = wave >> 1, wx = wave & 1;
  const int lq = lane >> 4, lr = lane & 15;
  const int nwg = gridDim.x;
  const int orig = blockIdx.x;
  const int blk = (orig & 7) * (nwg >> 3) + (orig >> 3);
  const int m0 = blk * 64;

  // keep-mask from top[] presence scan (one block; top final since routepack)
  if (orig == 0){
    int pres = 0;
    for (int i = tid; i < NTOK; i += 256) pres |= 1 << top[i];
    #pragma unroll
    for (int off = 32; off; off >>= 1) pres |= __shfl_down(pres, off, 64);
    if (lane == 0) presw[wave] = pres;
    __syncthreads();
    if (tid < T_){
      int all = presw[0] | presw[1] | presw[2] | presw[3];
      out_mask[tid] = ((all >> tid) & 1) ? 0.0f : 1.0f;
    }
    __syncthreads();
  }

  float t1v[8], t2v[8]; int t1i[8];
  #pragma unroll
  for (int q = 0; q < 8; ++q){ t1v[q] = INFINITY; t2v[q] = INFINITY; t1i[q] = 0x7fffffff; }

  for (int nc = 0; nc < 4; ++nc){
    const int n0c = nc * 128;
    floatx4 acc[2][4] = {};
    for (int k0 = 0; k0 < LAT; k0 += 32){
      {
        int mrel = tid >> 2, kc = (tid & 3) * 8;
        gload_lds16(A + (size_t)(m0+mrel) * LAT + k0 + kc, &As[(wave*64) * 8]);
      }
      #pragma unroll
      for (int c = 0; c < 2; ++c){
        int chunk = tid + c*256;
        int mrel = chunk >> 2, kc = (chunk & 3) * 8;
        gload_lds16(BT + (size_t)(n0c+mrel) * LAT + k0 + kc, &Bs[(c*256 + wave*64) * 8]);
      }
      __syncthreads();
      short8 af[2], bf[4];
      #pragma unroll
      for (int i = 0; i < 2; ++i)
        af[i] = *(const short8*)&As[(wy*32 + i*16 + lr)*32 + lq*8];
      #pragma unroll
      for (int j = 0; j < 4; ++j)
        bf[j] = *(const short8*)&Bs[(wx*64 + j*16 + lr)*32 + lq*8];
      #pragma unroll
      for (int i = 0; i < 2; ++i)
        #pragma unroll
        for (int j = 0; j < 4; ++j)
          acc[i][j] = __builtin_amdgcn_mfma_f32_16x16x32_bf16(af[i], bf[j], acc[i][j], 0, 0, 0);
      __syncthreads();
    }
    // fold this chunk's scores into running per-row top-2 (ascending cols)
    #pragma unroll
    for (int j = 0; j < 4; ++j){
      int col = n0c + wx*64 + j*16 + lr;
      float sv = svec[col];
      #pragma unroll
      for (int i = 0; i < 2; ++i){
        #pragma unroll
        for (int r = 0; r < 4; ++r){
          int q = i*4 + r;
          float s = sv - 2.f * acc[i][j][r];
          if (s < t1v[q]){ t2v[q] = t1v[q]; t1v[q] = s; t1i[q] = col; }
          else t2v[q] = fminf(t2v[q], s);
        }
      }
    }
  }

  // butterfly across the 16-lane col group (same rows, different cols)
  #pragma unroll
  for (int q = 0; q < 8; ++q){
    float v1 = t1v[q]; int i1 = t1i[q]; float v2 = t2v[q];
    #pragma unroll
    for (int m = 8; m; m >>= 1){
      float ov1 = __shfl_xor(v1, m, 64);
      int   oi1 = __shfl_xor(i1, m, 64);
      float ov2 = __shfl_xor(v2, m, 64);
      if (ov1 < v1 || (ov1 == v1 && oi1 < i1)){ v2 = fminf(v1, ov2); v1 = ov1; i1 = oi1; }
      else v2 = fminf(v2, ov1);
    }
    if (lr == 0){
      int row = wy*32 + (q>>2)*16 + lq*4 + (q&3);
      red_v1[row][wx] = v1; red_i1[row][wx] = i1; red_v2[row][wx] = v2;
    }
  }
  __syncthreads();
  // merge the two col-half waves; write idx, flag near-ties
  if (tid < 64){
    float v1 = red_v1[tid][0]; int i1 = red_i1[tid][0]; float v2 = red_v2[tid][0];
    float ov1 = red_v1[tid][1]; int oi1 = red_i1[tid][1]; float ov2 = red_v2[tid][1];
    if (ov1 < v1 || (ov1 == v1 && oi1 < i1)){ v2 = fminf(v1, ov2); v1 = ov1; i1 = oi1; }
    else v2 = fminf(v2, ov1);
    ridx[tid] = i1;
    out_idx[m0 + tid] = (float)i1;
    if (v2 - v1 < TAU){
      int p = atomicAdd(rcount, 1); rlist[p] = m0 + tid;
    }
  }
  __syncthreads();
  // codebook gather for the 64 rows
  #pragma unroll
  for (int rr = 0; rr < 16; ++rr){
    int row = rr*4 + wave;
    int idx = ridx[row];
    float4 cv = *(const float4*)(cb + (size_t)idx * SYM + lane * 4);
    *(float4*)(out_q + (size_t)(m0+row) * SYM + lane * 4) = cv;
    ushort4 qh; qh.x = f2bf(cv.x); qh.y = f2bf(cv.y); qh.z = f2bf(cv.z); qh.w = f2bf(cv.w);
    *(ushort4*)(q_h + (size_t)(m0+row) * SYM + lane * 4) = qh;
  }
}

// ---------------- exact f32 repair for near-tie tokens ----------------------
constexpr int RT = 4;

__global__ __launch_bounds__(256)
void repair_k(const int* __restrict__ rcount, const int* __restrict__ rlist,
              const int* __restrict__ top,
              const float* __restrict__ ts, const float* __restrict__ bus,
              const float* __restrict__ Wcomb, const float* __restrict__ rb,
              const float* __restrict__ cb, const float* __restrict__ cnorm,
              float* __restrict__ out_q, float* __restrict__ out_idx,
              unsigned short* __restrict__ q_h){
  __shared__ float a[RT][2*LAT];       // 32 KB
  __shared__ float raw[RT][SYM];       // 4 KB
  __shared__ float pv[RT][4];
  __shared__ int   pi[RT][4];
  __shared__ int   fidx[RT];
  int tid = threadIdx.x;
  int lane = tid & 63, wave = tid >> 6;
  int cnt = *rcount;
  int nchunk = (cnt + RT - 1) / RT;
  for (int ch = blockIdx.x; ch < nchunk; ch += gridDim.x){
    int base = ch * RT;
    int nt = min(RT, cnt - base);
    for (int q = tid; q < nt * 512; q += 256){
      int t = q >> 9, c = (q & 511) * 4;
      int m = rlist[base + t];
      int tp = top[m];
      float4 v = (c < LAT) ? *(const float4*)(ts + (size_t)m * LAT + c)
                           : *(const float4*)(bus + ((size_t)tp * NTOK + m) * LAT + (c - LAT));
      *(float4*)&a[t][c] = v;
    }
    __syncthreads();
    float acc0[RT], acc1[RT], acc2[RT], acc3[RT];
    #pragma unroll
    for (int t = 0; t < RT; ++t){ acc0[t]=0.f; acc1[t]=0.f; acc2[t]=0.f; acc3[t]=0.f; }
    for (int k = 0; k < 2*LAT; k += 4){
      float w0 = Wcomb[(size_t)(k+0) * SYM + tid];
      float w1 = Wcomb[(size_t)(k+1) * SYM + tid];
      float w2 = Wcomb[(size_t)(k+2) * SYM + tid];
      float w3 = Wcomb[(size_t)(k+3) * SYM + tid];
      #pragma unroll
      for (int t = 0; t < RT; ++t){
        float4 av = *(const float4*)&a[t][k];
        acc0[t] += av.x * w0; acc1[t] += av.y * w1;
        acc2[t] += av.z * w2; acc3[t] += av.w * w3;
      }
    }
    #pragma unroll
    for (int t = 0; t < RT; ++t)
      raw[t][tid] = rb[tid] + ((acc0[t] + acc1[t]) + (acc2[t] + acc3[t]));
    __syncthreads();
    float bv[RT]; int bi[RT];
    #pragma unroll
    for (int t = 0; t < RT; ++t){ bv[t] = INFINITY; bi[t] = 0x7fffffff; }
    #pragma unroll
    for (int cc = 0; cc < 2; ++cc){
      int c = tid + cc * 256;
      const float* cr = cb + (size_t)c * SYM;
      float d[RT] = {};
      for (int j = 0; j < SYM; j += 4){
        float4 cv = *(const float4*)(cr + j);
        #pragma unroll
        for (int t = 0; t < RT; ++t){
          float4 rv4 = *(const float4*)&raw[t][j];
          d[t] += rv4.x*cv.x + rv4.y*cv.y + rv4.z*cv.z + rv4.w*cv.w;
        }
      }
      #pragma unroll
      for (int t = 0; t < RT; ++t){
        float s = cnorm[c] - 2.f * d[t];
        if (s < bv[t] || (s == bv[t] && c < bi[t])){ bv[t] = s; bi[t] = c; }
      }
    }
    #pragma unroll
    for (int t = 0; t < RT; ++t){
      float v = bv[t]; int i = bi[t];
      #pragma unroll
      for (int off = 32; off; off >>= 1){
        float ov = __shfl_down(v, off, 64);
        int   oi = __shfl_down(i, off, 64);
        if (ov < v || (ov == v && oi < i)){ v = ov; i = oi; }
      }
      if (lane == 0){ pv[t][wave] = v; pi[t][wave] = i; }
    }
    __syncthreads();
    if (tid < nt){
      float v = pv[tid][0]; int i = pi[tid][0];
      #pragma unroll
      for (int w = 1; w < 4; ++w){
        if (pv[tid][w] < v || (pv[tid][w] == v && pi[tid][w] < i)){ v = pv[tid][w]; i = pi[tid][w]; }
      }
      fidx[tid] = i;
      out_idx[rlist[base + tid]] = (float)i;
    }
    __syncthreads();
    for (int t = 0; t < nt; ++t){
      int m = rlist[base + t];
      int idx = fidx[t];
      float cvv = cb[(size_t)idx * SYM + tid];
      out_q[(size_t)m * SYM + tid] = cvv;
      q_h[(size_t)m * SYM + tid] = f2bf(cvv);
    }
    __syncthreads();   // protect a/raw/fidx reuse across chunks
  }
}

} // namespace

extern "C" void kernel_launch(void* const* d_in, const int* in_sizes, int n_in,
                              void* d_out, int out_size, void* d_ws, size_t ws_size,
                              hipStream_t stream){
  const float* token_state = (const float*)d_in[0];
  const float* bus_symbols = (const float*)d_in[1];
  const float* bus_outputs = (const float*)d_in[3];
  const float* Wq    = (const float*)d_in[5];
  const float* Wread = (const float*)d_in[7];
  const float* bread = (const float*)d_in[8];
  const float* Wsym  = (const float*)d_in[9];
  const float* bsym  = (const float*)d_in[10];
  const float* Wc1   = (const float*)d_in[11];
  const float* bc1   = (const float*)d_in[12];
  const float* Wc2   = (const float*)d_in[13];
  const float* bc2   = (const float*)d_in[14];
  const float* codebook = (const float*)d_in[15];

  float* out_node = (float*)d_out;                       // [NTOK*LAT]
  float* out_quant= out_node + (size_t)NTOK * LAT;       // [NTOK*SYM]
  float* out_idx  = out_quant + (size_t)NTOK * SYM;      // [NTOK]
  float* out_mask = out_idx + NTOK;                      // [T]

  // ---- workspace layout (256B aligned) ----
  char* W = (char*)d_ws; size_t off = 0;
  auto alloc = [&](size_t bytes)->char*{ char* p = W + off; off = (off + bytes + 255) & ~(size_t)255; return p; };
  int*   top     = (int*)alloc(NTOK*4);
  int*   rcount  = (int*)alloc(256);
  int*   rlist   = (int*)alloc(NTOK*4);
  float* cnorm   = (float*)alloc(NC*4);
  float* svec    = (float*)alloc(NC*4);
  float* rb      = (float*)alloc(SYM*4);
  float* Wcomb   = (float*)alloc((size_t)2*LAT*SYM*4);
  unsigned short* WreadT = (unsigned short*)alloc((size_t)LAT*2*LAT*2);
  unsigned short* Wc1T   = (unsigned short*)alloc((size_t)LAT*(LAT+SYM)*2);
  unsigned short* Wc2T   = (unsigned short*)alloc((size_t)LAT*LAT*2);
  unsigned short* WfuseT = (unsigned short*)alloc((size_t)NC*LAT*2);
  unsigned short* z_h    = (unsigned short*)alloc((size_t)NTOK*LAT*2);
  unsigned short* q_h    = (unsigned short*)alloc((size_t)NTOK*SYM*2);
  unsigned short* h_h    = (unsigned short*)alloc((size_t)NTOK*LAT*2);
  unsigned short* A_z    = (unsigned short*)alloc((size_t)NTOK*2*LAT*2);

  // routing + A_z pack (one wave per token); zeroes rcount
  routepack_k<<<NTOK/4, 256, 0, stream>>>(bus_symbols, Wq, token_state, bus_outputs,
                                          top, rcount, A_z);
  // all weight prep in one dispatch
  megaprep_k<<<MP_CNORM + 1, 256, 0, stream>>>(
      Wsym, codebook, WfuseT, Wread, Wcomb, WreadT, Wc1, Wc1T, Wc2, Wc2T,
      bsym, cnorm, svec, bread, rb);

  // z_h = bf16(A_z @ WreadT^T + bread)   [NTOK x LAT]
  mgemm<A_PLAIN, EP_ZH><<<dim3(LAT/128, NTOK/128), 256, 0, stream>>>(
      A_z, nullptr, WreadT, bread, nullptr, z_h, nullptr, LAT, 2*LAT, 0);

  // fused: scores GEMM + top-2 argmin + gather + repair flags + keep-mask
  vqgemm_k<<<NTOK/64, 256, 0, stream>>>(z_h, WfuseT, svec, codebook, top,
                                        out_quant, out_idx, q_h, rcount, rlist, out_mask);

  repair_k<<<512, 256, 0, stream>>>(rcount, rlist, top, token_state, bus_outputs,
                                    Wcomb, rb, codebook, cnorm, out_quant, out_idx, q_h);

  // h_h = bf16(relu([z_h | q_h] @ Wc1T^T + bc1))
  mgemm<A_CAT, EP_RELU><<<dim3(LAT/128, NTOK/128), 256, 0, stream>>>(
      z_h, q_h, Wc1T, bc1, nullptr, h_h, nullptr, LAT, LAT+SYM, LAT);
  // out_node = h_h @ Wc2T^T + bc2 + token_state   (f32)
  mgemm<A_PLAIN, EP_OUT><<<dim3(LAT/128, NTOK/128), 256, 0, stream>>>(
      h_h, nullptr, Wc2T, bc2, token_state, nullptr, out_node, LAT, LAT, 0);
}